// Round 4
// baseline (248.217 us; speedup 1.0000x reference)
//
#include <hip/hip_runtime.h>
#include <stdint.h>

// Problem constants (B,T,D,H fixed by the reference)
#define B_SZ 2
#define T_SEQ 2048
#define DMODEL 1024
#define NHEAD 16
#define DKH 64
#define M_ROWS (B_SZ * T_SEQ)   // 4096

#define LDT 72    // padded LDS row stride (bf16) for VALU-written tiles (sP): 2-way = free

#define INP_E  4194304u   // 4M elems per input tensor
#define W_E    1048576u   // 1M elems per weight

typedef __bf16 bf16x8 __attribute__((ext_vector_type(8)));
typedef float  f32x4  __attribute__((ext_vector_type(4)));

__device__ __forceinline__ unsigned short f2bf(float f) {
    unsigned u = __builtin_bit_cast(unsigned, f);
    u += 0x7fffu + ((u >> 16) & 1u);   // RNE
    return (unsigned short)(u >> 16);
}
// 8 consecutive fp32 -> 8 bf16 packed in a uint4
__device__ __forceinline__ uint4 cvt8(const float* p) {
    float4 f0 = *(const float4*)p, f1 = *(const float4*)(p + 4);
    uint4 r;
    r.x = (unsigned)f2bf(f0.x) | ((unsigned)f2bf(f0.y) << 16);
    r.y = (unsigned)f2bf(f0.z) | ((unsigned)f2bf(f0.w) << 16);
    r.z = (unsigned)f2bf(f1.x) | ((unsigned)f2bf(f1.y) << 16);
    r.w = (unsigned)f2bf(f1.z) | ((unsigned)f2bf(f1.w) << 16);
    return r;
}

// Async global->LDS, 16B per lane. LDS dest = wave-uniform base + lane*16 (m104/m108).
__device__ __forceinline__ void async16(const unsigned short* g, unsigned short* l) {
    __builtin_amdgcn_global_load_lds(
        (const __attribute__((address_space(1))) void*)g,
        (__attribute__((address_space(3))) void*)l, 16, 0, 0);
}

// One-shot fp32 -> bf16 conversion of q,k,v + 4 weights into ws.
__global__ __launch_bounds__(256) void cvt_all(
    const float* __restrict__ q, const float* __restrict__ k, const float* __restrict__ v,
    const float* __restrict__ wq, const float* __restrict__ wk,
    const float* __restrict__ wv, const float* __restrict__ wo,
    unsigned short* __restrict__ wsb)
{
    int blk = blockIdx.x;
    const float* src; unsigned short* dst; int lb;
    if      (blk < 2048) { src = q;  dst = wsb;                       lb = blk; }
    else if (blk < 4096) { src = k;  dst = wsb + INP_E;               lb = blk - 2048; }
    else if (blk < 6144) { src = v;  dst = wsb + 2 * INP_E;           lb = blk - 4096; }
    else if (blk < 6656) { src = wq; dst = wsb + 3 * INP_E;           lb = blk - 6144; }
    else if (blk < 7168) { src = wk; dst = wsb + 3 * INP_E + W_E;     lb = blk - 6656; }
    else if (blk < 7680) { src = wv; dst = wsb + 3 * INP_E + 2 * W_E; lb = blk - 7168; }
    else                 { src = wo; dst = wsb + 3 * INP_E + 3 * W_E; lb = blk - 7680; }
    size_t i = ((size_t)lb * 256 + threadIdx.x) * 8;
    *(uint4*)&dst[i] = cvt8(src + i);
}

// ---------------- m97-style GEMM core ----------------
// D[m][n] = sum_k A[m][k]*W[n][k] + bias. Tile (MT*32) x 128, BK=64,
// global_load_lds width=16 into UNPADDED stride-64 LDS with XOR column-chunk
// swizzle (LDS[row][j] holds global chunk j^(row&7); reads un-swizzle).
// C_MODE: 0 = bf16 C[m*N+n] (bias[n]); 1 = fp32 C (bias[n]);
//         2 = Vt[(b*1024+m)*2048 + t] (bias[m], transposed store).
template<int C_MODE, int MT>
__device__ __forceinline__ void gemm_core(
    const unsigned short* __restrict__ A, const unsigned short* __restrict__ W,
    const float* __restrict__ bias, void* __restrict__ C,
    int N, int K, int bx, int by,
    unsigned short* sA, unsigned short* sB)
{
    const int tid  = threadIdx.x;
    const int wave = tid >> 6, lane = tid & 63;
    const int quad = lane >> 4, l15 = lane & 15;
    const int TM = MT * 32;
    const int m0 = by * TM, n0 = bx * 128;
    const int wm = (wave & 1) * (MT * 16), wn = (wave >> 1) * 64;

    f32x4 acc[MT][4] = {};

    for (int k0 = 0; k0 < K; k0 += 64) {
        __syncthreads();                      // prev iteration's LDS reads done
        #pragma unroll
        for (int i = 0; i < MT; i++) {        // A: TM rows x 8 chunks
            int c   = tid + 256 * i;
            int row = c >> 3;
            int gk  = ((c & 7) ^ (row & 7)) * 8;
            int sb  = (wave * 64 + 256 * i) * 8;
            async16(&A[(size_t)(m0 + row) * K + k0 + gk], sA + sb);
        }
        #pragma unroll
        for (int i = 0; i < 4; i++) {         // B: 128 rows x 8 chunks
            int c   = tid + 256 * i;
            int row = c >> 3;
            int gk  = ((c & 7) ^ (row & 7)) * 8;
            int sb  = (wave * 64 + 256 * i) * 8;
            async16(&W[(size_t)(n0 + row) * K + k0 + gk], sB + sb);
        }
        __syncthreads();                      // drains vmcnt(0): data landed
        const int sw = l15 & 7;
        #pragma unroll
        for (int ks = 0; ks < 2; ks++) {
            bf16x8 af[MT], bfv[4];
            #pragma unroll
            for (int mt = 0; mt < MT; mt++)
                af[mt] = *(const bf16x8*)&sA[(wm + mt * 16 + l15) * 64 +
                                             (((ks * 4 + quad) ^ sw) * 8)];
            #pragma unroll
            for (int nt = 0; nt < 4; nt++)
                bfv[nt] = *(const bf16x8*)&sB[(wn + nt * 16 + l15) * 64 +
                                              (((ks * 4 + quad) ^ sw) * 8)];
            #pragma unroll
            for (int mt = 0; mt < MT; mt++)
                #pragma unroll
                for (int nt = 0; nt < 4; nt++)
                    acc[mt][nt] = __builtin_amdgcn_mfma_f32_16x16x32_bf16(
                        af[mt], bfv[nt], acc[mt][nt], 0, 0, 0);
        }
    }

    if (C_MODE == 2) {
        #pragma unroll
        for (int mt = 0; mt < MT; mt++) {
            #pragma unroll
            for (int r = 0; r < 4; r++) {
                int m = m0 + wm + mt * 16 + quad * 4 + r;
                float bm = bias[m];
                #pragma unroll
                for (int nt = 0; nt < 4; nt++) {
                    int n = n0 + wn + nt * 16 + l15;
                    int bb = n >> 11, t = n & 2047;
                    ((unsigned short*)C)[((size_t)bb * 1024 + m) * 2048 + t] =
                        f2bf(acc[mt][nt][r] + bm);
                }
            }
        }
    } else {
        #pragma unroll
        for (int nt = 0; nt < 4; nt++) {
            int n = n0 + wn + nt * 16 + l15;
            float bv = bias[n];
            #pragma unroll
            for (int mt = 0; mt < MT; mt++) {
                #pragma unroll
                for (int r = 0; r < 4; r++) {
                    int m = m0 + wm + mt * 16 + quad * 4 + r;   // D row = quad*4+reg
                    float val = acc[mt][nt][r] + bv;
                    if (C_MODE == 1) ((float*)C)[(size_t)m * N + n] = val;
                    else ((unsigned short*)C)[(size_t)m * N + n] = f2bf(val);
                }
            }
        }
    }
}

// Q,K,V projections + V-transpose batched: grid (256,1,3) = 768 blocks (~3/CU).
__global__ __launch_bounds__(256) void gemm_qkv(
    const unsigned short* __restrict__ Qb, const unsigned short* __restrict__ Kb,
    const unsigned short* __restrict__ Vb,
    const unsigned short* __restrict__ Wqb, const unsigned short* __restrict__ Wkb,
    const unsigned short* __restrict__ Wvb,
    const float* __restrict__ bq, const float* __restrict__ bk, const float* __restrict__ bv,
    unsigned short* __restrict__ Qp, unsigned short* __restrict__ Kp,
    unsigned short* __restrict__ Vt)
{
    __shared__ __align__(16) unsigned short sA[128 * 64];
    __shared__ __align__(16) unsigned short sB[128 * 64];
    const int z = blockIdx.z, id = blockIdx.x;
    if (z < 2) {
        gemm_core<0, 4>(z ? Kb : Qb, z ? Wkb : Wqb, z ? bk : bq, z ? Kp : Qp,
                        DMODEL, DMODEL, id & 7, id >> 3, sA, sB);
    } else {
        gemm_core<2, 4>(Wvb, Vb, bv, Vt, M_ROWS, DMODEL, id & 31, id >> 5, sA, sB);
    }
}

// Output projection: 64x128 tiles -> 512 blocks (2/CU hides the barrier drain).
__global__ __launch_bounds__(256) void gemm_o(
    const unsigned short* __restrict__ AO, const unsigned short* __restrict__ Wob,
    const float* __restrict__ bo, float* __restrict__ out)
{
    __shared__ __align__(16) unsigned short sA[64 * 64];
    __shared__ __align__(16) unsigned short sB[128 * 64];
    const int id = blockIdx.x;
    gemm_core<1, 2>(AO, Wob, bo, out, DMODEL, DMODEL, id & 7, id >> 3, sA, sB);
}

// ---------------- flash attention: 2-phase double-buffered, 32 q-rows/wave ----------------
// Round-2 restructure: LDS-traffic-bound (2.6 GB of ds_read at ~69 TB/s ceiling
// explained the 64 us). Each wave now owns TWO 16-row M-tiles (32 q-rows), so the
// same 16 KB K/V tile read feeds 32 MFMAs instead of 16: LDS bytes/iter/wave
// 20 KB -> 24 KB but wave-iters HALVE => total 2.6 GB -> 1.6 GB. 4 waves/block,
// QBLK=128, grid 512 (2 blocks/CU by LDS = 58 KB). Single barrier per tile;
// double-buffered K/V prefetch issued a full tile of compute ahead.
#define QBLK 128
#define KVB 64
#define AW 4          // waves per attn block

__global__ __launch_bounds__(256) void attn_kernel(
    const unsigned short* __restrict__ Qp,
    const unsigned short* __restrict__ Kp,
    const unsigned short* __restrict__ Vt,
    const int* __restrict__ maskp,     // [B,T], nonzero = keep
    unsigned short* __restrict__ Op)
{
    __shared__ __align__(16) unsigned short sK[2][KVB * 64];    // [s][d], swizzled
    __shared__ __align__(16) unsigned short sV[2][KVB * 64];    // [d][s], swizzled
    __shared__ __align__(16) unsigned short sP[AW * 32 * LDT];  // per-wave P [q][s], padded
    __shared__ float smf[T_SEQ];                                // 0 or -30000 per key col

    const int tid  = threadIdx.x;
    const int wave = tid >> 6, lane = tid & 63;
    const int quad = lane >> 4, l15 = lane & 15;
    const int qblk = blockIdx.x, h = blockIdx.y, b = blockIdx.z;

    const float SCL2 = 0.125f * 1.44269504089f;   // 1/sqrt(DK) * log2(e)
    const float MNEG = -30000.f;                  // exp2(-30000+x) == 0

    // Q fragments for both M-tiles (rows wave*32 + mt*16 + l15)
    bf16x8 aq[2][2];
    #pragma unroll
    for (int mt = 0; mt < 2; mt++) {
        const int qrow = qblk * QBLK + wave * 32 + mt * 16 + l15;
        const unsigned short* qptr =
            Qp + (size_t)(b * T_SEQ + qrow) * DMODEL + h * DKH + quad * 8;
        aq[mt][0] = *(const bf16x8*)qptr;
        aq[mt][1] = *(const bf16x8*)(qptr + 32);
    }

    const unsigned short* Kb_ = Kp + (size_t)b * T_SEQ * DMODEL + h * DKH;
    const unsigned short* VtB = Vt + ((size_t)b * DMODEL + h * DKH) * T_SEQ;

    f32x4 O[2][4] = {};
    float l_r[2][4] = {};
    unsigned short* sPw = sP + wave * 32 * LDT;

    // prologue: stage tile 0 (512 chunks of 16B over 256 threads), expand mask
    #pragma unroll
    for (int i = 0; i < 2; i++) {
        int c   = tid + 256 * i;
        int row = c >> 3;
        int gk  = ((c & 7) ^ (row & 7)) * 8;   // swizzled global chunk
        int sb  = (wave * 64 + 256 * i) * 8;   // wave-uniform LDS base (elems)
        async16(&Kb_[(size_t)row * DMODEL + gk], &sK[0][sb]);
        async16(&VtB[(size_t)row * T_SEQ + gk], &sV[0][sb]);
    }
    #pragma unroll
    for (int j = 0; j < 8; j++) {
        int i = tid + 256 * j;
        smf[i] = maskp[b * T_SEQ + i] ? 0.f : MNEG;
    }
    __syncthreads();    // drains tile-0 stage + mask writes

    const int sw = l15 & 7;
    for (int t = 0; t < T_SEQ / KVB; ++t) {
        const int cur = t & 1;
        const int s0 = t * KVB;
        // ---- prefetch tile t+1 into the other buffer (overlaps this tile's compute)
        if (t + 1 < T_SEQ / KVB) {
            #pragma unroll
            for (int i = 0; i < 2; i++) {
                int c   = tid + 256 * i;
                int row = c >> 3;
                int gk  = ((c & 7) ^ (row & 7)) * 8;
                int sb  = (wave * 64 + 256 * i) * 8;
                async16(&Kb_[(size_t)(s0 + KVB + row) * DMODEL + gk], &sK[cur ^ 1][sb]);
                async16(&VtB[(size_t)row * T_SEQ + s0 + KVB + gk], &sV[cur ^ 1][sb]);
            }
        }

        // ---- S = Q K^T for both M-tiles; softmax; P -> LDS ----
        #pragma unroll
        for (int mt = 0; mt < 2; mt++) {
            f32x4 S[4];
            __builtin_amdgcn_s_setprio(1);
            #pragma unroll
            for (int nt = 0; nt < 4; nt++) {
                const unsigned short* kr = &sK[cur][(nt * 16 + l15) * 64];
                f32x4 z = {};
                z = __builtin_amdgcn_mfma_f32_16x16x32_bf16(
                    aq[mt][0], *(const bf16x8*)&kr[(quad ^ sw) * 8], z, 0, 0, 0);
                z = __builtin_amdgcn_mfma_f32_16x16x32_bf16(
                    aq[mt][1], *(const bf16x8*)&kr[((quad + 4) ^ sw) * 8], z, 0, 0, 0);
                S[nt] = z;
            }
            __builtin_amdgcn_s_setprio(0);
            #pragma unroll
            for (int nt = 0; nt < 4; nt++) {
                float madd = smf[s0 + nt * 16 + l15];
                #pragma unroll
                for (int r = 0; r < 4; r++) {
                    float p = __builtin_amdgcn_exp2f(fmaf(S[nt][r], SCL2, madd));
                    l_r[mt][r] += p;
                    unsigned u = __builtin_bit_cast(unsigned, p) + 0x8000u;  // round-half-up
                    sPw[(mt * 16 + quad * 4 + r) * LDT + nt * 16 + l15] =
                        (unsigned short)(u >> 16);
                }
            }
        }
        // NO barrier: sPw is per-wave private; intra-wave ds ordering via lgkmcnt.

        // ---- O += P V  (A = P rows, B = V^T rows) ----
        #pragma unroll
        for (int mt = 0; mt < 2; mt++) {
            const bf16x8 ap0 = *(const bf16x8*)&sPw[(mt * 16 + l15) * LDT + quad * 8];
            const bf16x8 ap1 = *(const bf16x8*)&sPw[(mt * 16 + l15) * LDT + 32 + quad * 8];
            __builtin_amdgcn_s_setprio(1);
            #pragma unroll
            for (int nt = 0; nt < 4; nt++) {
                const unsigned short* vr = &sV[cur][(nt * 16 + l15) * 64];
                O[mt][nt] = __builtin_amdgcn_mfma_f32_16x16x32_bf16(
                    ap0, *(const bf16x8*)&vr[(quad ^ sw) * 8], O[mt][nt], 0, 0, 0);
                O[mt][nt] = __builtin_amdgcn_mfma_f32_16x16x32_bf16(
                    ap1, *(const bf16x8*)&vr[((quad + 4) ^ sw) * 8], O[mt][nt], 0, 0, 0);
            }
            __builtin_amdgcn_s_setprio(0);
        }

        // single barrier: drains prefetch (vmcnt->0) AND guarantees all waves
        // finished reading buf[cur] before iteration t+1 overwrites it.
        __syncthreads();
    }

    // ---- row-sum reduce, normalize, write AO [B,T,D] ----
    #pragma unroll
    for (int mt = 0; mt < 2; mt++) {
        #pragma unroll
        for (int r = 0; r < 4; r++) {
            float l = l_r[mt][r];
            l += __shfl_xor(l, 1);
            l += __shfl_xor(l, 2);
            l += __shfl_xor(l, 4);
            l += __shfl_xor(l, 8);
            l_r[mt][r] = 1.0f / fmaxf(l, 1e-30f);
        }
        #pragma unroll
        for (int nt = 0; nt < 4; nt++) {
            #pragma unroll
            for (int r = 0; r < 4; r++) {
                int q = qblk * QBLK + wave * 32 + mt * 16 + quad * 4 + r;
                Op[(size_t)(b * T_SEQ + q) * DMODEL + h * DKH + nt * 16 + l15] =
                    f2bf(O[mt][nt][r] * l_r[mt][r]);
            }
        }
    }
}

// ---------------- legacy fp32-staging GEMM (fallback path only) ----------------
template<int A_BF16, int W_BF16, int C_MODE>
__global__ __launch_bounds__(256) void gemm_bt_cvt(
    const void* __restrict__ A_, const void* __restrict__ W_,
    const float* __restrict__ bias, void* __restrict__ C_,
    int M, int N, int K)
{
    __shared__ __align__(16) unsigned short sA[128 * LDT];
    __shared__ __align__(16) unsigned short sB[128 * LDT];
    const int tid  = threadIdx.x;
    const int wave = tid >> 6, lane = tid & 63;
    const int quad = lane >> 4, l15 = lane & 15;
    const int m0 = blockIdx.y * 128, n0 = blockIdx.x * 128;
    const int wm = (wave & 1) * 64, wn = (wave >> 1) * 64;
    f32x4 acc[4][4] = {};
    for (int k0 = 0; k0 < K; k0 += 64) {
        __syncthreads();
        #pragma unroll
        for (int i = 0; i < 4; i++) {
            int c = tid + 256 * i;
            int row = c >> 3, koff = (c & 7) * 8;
            if (A_BF16)
                *(uint4*)&sA[row * LDT + koff] =
                    *(const uint4*)&((const unsigned short*)A_)[(size_t)(m0 + row) * K + k0 + koff];
            else
                *(uint4*)&sA[row * LDT + koff] =
                    cvt8((const float*)A_ + (size_t)(m0 + row) * K + k0 + koff);
            if (W_BF16)
                *(uint4*)&sB[row * LDT + koff] =
                    *(const uint4*)&((const unsigned short*)W_)[(size_t)(n0 + row) * K + k0 + koff];
            else
                *(uint4*)&sB[row * LDT + koff] =
                    cvt8((const float*)W_ + (size_t)(n0 + row) * K + k0 + koff);
        }
        __syncthreads();
        #pragma unroll
        for (int ks = 0; ks < 2; ks++) {
            bf16x8 af[4], bfr[4];
            #pragma unroll
            for (int mt = 0; mt < 4; mt++)
                af[mt] = *(const bf16x8*)&sA[(wm + mt * 16 + l15) * LDT + ks * 32 + quad * 8];
            #pragma unroll
            for (int nt = 0; nt < 4; nt++)
                bfr[nt] = *(const bf16x8*)&sB[(wn + nt * 16 + l15) * LDT + ks * 32 + quad * 8];
            #pragma unroll
            for (int mt = 0; mt < 4; mt++)
                #pragma unroll
                for (int nt = 0; nt < 4; nt++)
                    acc[mt][nt] = __builtin_amdgcn_mfma_f32_16x16x32_bf16(
                        af[mt], bfr[nt], acc[mt][nt], 0, 0, 0);
        }
    }
    if (C_MODE == 2) {
        #pragma unroll
        for (int mt = 0; mt < 4; mt++)
            #pragma unroll
            for (int r = 0; r < 4; r++) {
                int m = m0 + wm + mt * 16 + quad * 4 + r;
                float bm = bias[m];
                #pragma unroll
                for (int nt = 0; nt < 4; nt++) {
                    int n = n0 + wn + nt * 16 + l15;
                    int bb = n >> 11, t = n & 2047;
                    ((unsigned short*)C_)[((size_t)bb * 1024 + m) * 2048 + t] =
                        f2bf(acc[mt][nt][r] + bm);
                }
            }
    } else {
        #pragma unroll
        for (int nt = 0; nt < 4; nt++) {
            int n = n0 + wn + nt * 16 + l15;
            float bv = bias[n];
            #pragma unroll
            for (int mt = 0; mt < 4; mt++)
                #pragma unroll
                for (int r = 0; r < 4; r++) {
                    int m = m0 + wm + mt * 16 + quad * 4 + r;
                    float val = acc[mt][nt][r] + bv;
                    if (C_MODE == 1) ((float*)C_)[(size_t)m * N + n] = val;
                    else ((unsigned short*)C_)[(size_t)m * N + n] = f2bf(val);
                }
        }
    }
}

extern "C" void kernel_launch(void* const* d_in, const int* in_sizes, int n_in,
                              void* d_out, int out_size, void* d_ws, size_t ws_size,
                              hipStream_t stream)
{
    const float* q  = (const float*)d_in[0];
    const float* k  = (const float*)d_in[1];
    const float* v  = (const float*)d_in[2];
    const int*   mk = (const int*)d_in[3];
    const float* Wq = (const float*)d_in[4];
    const float* bq = (const float*)d_in[5];
    const float* Wk = (const float*)d_in[6];
    const float* bk = (const float*)d_in[7];
    const float* Wv = (const float*)d_in[8];
    const float* bv = (const float*)d_in[9];
    const float* Wo = (const float*)d_in[10];
    const float* bo = (const float*)d_in[11];
    float* out = (float*)d_out;

    unsigned short* wsb = (unsigned short*)d_ws;
    const dim3 gA(T_SEQ / QBLK, NHEAD, B_SZ);   // 16 x 16 x 2 = 512 blocks

    if (ws_size >= (size_t)64 * 1024 * 1024) {
        // Path A: pre-convert to bf16; m97-style global_load_lds GEMMs.
        unsigned short* Qb  = wsb;
        unsigned short* Kb  = wsb + INP_E;
        unsigned short* Vb  = wsb + 2 * INP_E;
        unsigned short* Wqb = wsb + 3 * INP_E;
        unsigned short* Wkb = wsb + 3 * INP_E + W_E;
        unsigned short* Wvb = wsb + 3 * INP_E + 2 * W_E;
        unsigned short* Wob = wsb + 3 * INP_E + 3 * W_E;
        unsigned short* Qp  = wsb + 4 * INP_E;
        unsigned short* Kp  = wsb + 5 * INP_E;
        unsigned short* Vt  = wsb + 6 * INP_E;
        unsigned short* AO  = wsb + 7 * INP_E;       // end = 64MB

        cvt_all<<<8192, 256, 0, stream>>>(q, k, v, Wq, Wk, Wv, Wo, wsb);
        gemm_qkv<<<dim3(256, 1, 3), 256, 0, stream>>>(
            Qb, Kb, Vb, Wqb, Wkb, Wvb, bq, bk, bv, Qp, Kp, Vt);
        attn_kernel<<<gA, 256, 0, stream>>>(Qp, Kp, Vt, mk, AO);
        gemm_o<<<dim3(512, 1, 1), 256, 0, stream>>>(AO, Wob, bo, out);
    } else {
        // Path C fallback: in-GEMM convert (32MB ws), legacy kernels.
        unsigned short* Qp = wsb;
        unsigned short* Kp = wsb + INP_E;
        unsigned short* Vt = wsb + 2 * INP_E;
        unsigned short* AO = wsb + 3 * INP_E;
        const dim3 gN(DMODEL / 128, M_ROWS / 128);
        const dim3 gV(M_ROWS / 128, DMODEL / 128);
        gemm_bt_cvt<0, 0, 0><<<gN, 256, 0, stream>>>(q, Wq, bq, Qp, M_ROWS, DMODEL, DMODEL);
        gemm_bt_cvt<0, 0, 0><<<gN, 256, 0, stream>>>(k, Wk, bk, Kp, M_ROWS, DMODEL, DMODEL);
        gemm_bt_cvt<0, 0, 2><<<gV, 256, 0, stream>>>(Wv, v, bv, Vt, DMODEL, M_ROWS, DMODEL);
        attn_kernel<<<gA, 256, 0, stream>>>(Qp, Kp, Vt, mk, AO);
        gemm_bt_cvt<1, 0, 1><<<gN, 256, 0, stream>>>(AO, Wo, bo, out, M_ROWS, DMODEL, DMODEL);
    }
}

// Round 5
// 237.925 us; speedup vs baseline: 1.0433x; 1.0433x over previous
//
#include <hip/hip_runtime.h>
#include <stdint.h>

// Problem constants (B,T,D,H fixed by the reference)
#define B_SZ 2
#define T_SEQ 2048
#define DMODEL 1024
#define NHEAD 16
#define DKH 64
#define M_ROWS (B_SZ * T_SEQ)   // 4096

#define LDT 72    // padded LDS row stride (bf16) for VALU-written tiles (sP): 2-way = free

#define INP_E  4194304u   // 4M elems per input tensor
#define W_E    1048576u   // 1M elems per weight

typedef __bf16 bf16x8 __attribute__((ext_vector_type(8)));
typedef float  f32x4  __attribute__((ext_vector_type(4)));

__device__ __forceinline__ unsigned short f2bf(float f) {
    unsigned u = __builtin_bit_cast(unsigned, f);
    u += 0x7fffu + ((u >> 16) & 1u);   // RNE
    return (unsigned short)(u >> 16);
}
// 8 consecutive fp32 -> 8 bf16 packed in a uint4
__device__ __forceinline__ uint4 cvt8(const float* p) {
    float4 f0 = *(const float4*)p, f1 = *(const float4*)(p + 4);
    uint4 r;
    r.x = (unsigned)f2bf(f0.x) | ((unsigned)f2bf(f0.y) << 16);
    r.y = (unsigned)f2bf(f0.z) | ((unsigned)f2bf(f0.w) << 16);
    r.z = (unsigned)f2bf(f1.x) | ((unsigned)f2bf(f1.y) << 16);
    r.w = (unsigned)f2bf(f1.z) | ((unsigned)f2bf(f1.w) << 16);
    return r;
}

// Async global->LDS, 16B per lane. LDS dest = wave-uniform base + lane*16 (m104/m108).
__device__ __forceinline__ void async16(const unsigned short* g, unsigned short* l) {
    __builtin_amdgcn_global_load_lds(
        (const __attribute__((address_space(1))) void*)g,
        (__attribute__((address_space(3))) void*)l, 16, 0, 0);
}

// One-shot fp32 -> bf16 conversion of q,k,v + 4 weights into ws.
__global__ __launch_bounds__(256) void cvt_all(
    const float* __restrict__ q, const float* __restrict__ k, const float* __restrict__ v,
    const float* __restrict__ wq, const float* __restrict__ wk,
    const float* __restrict__ wv, const float* __restrict__ wo,
    unsigned short* __restrict__ wsb)
{
    int blk = blockIdx.x;
    const float* src; unsigned short* dst; int lb;
    if      (blk < 2048) { src = q;  dst = wsb;                       lb = blk; }
    else if (blk < 4096) { src = k;  dst = wsb + INP_E;               lb = blk - 2048; }
    else if (blk < 6144) { src = v;  dst = wsb + 2 * INP_E;           lb = blk - 4096; }
    else if (blk < 6656) { src = wq; dst = wsb + 3 * INP_E;           lb = blk - 6144; }
    else if (blk < 7168) { src = wk; dst = wsb + 3 * INP_E + W_E;     lb = blk - 6656; }
    else if (blk < 7680) { src = wv; dst = wsb + 3 * INP_E + 2 * W_E; lb = blk - 7168; }
    else                 { src = wo; dst = wsb + 3 * INP_E + 3 * W_E; lb = blk - 7680; }
    size_t i = ((size_t)lb * 256 + threadIdx.x) * 8;
    *(uint4*)&dst[i] = cvt8(src + i);
}

// ---------------- m97-style GEMM core ----------------
// D[m][n] = sum_k A[m][k]*W[n][k] + bias. Tile (MT*32) x 128, BK=64,
// global_load_lds width=16 into UNPADDED stride-64 LDS with XOR column-chunk
// swizzle (LDS[row][j] holds global chunk j^(row&7); reads un-swizzle).
// C_MODE: 0 = bf16 C[m*N+n] (bias[n]); 1 = fp32 C (bias[n]);
//         2 = Vt[(b*1024+m)*2048 + t] (bias[m], transposed store).
template<int C_MODE, int MT>
__device__ __forceinline__ void gemm_core(
    const unsigned short* __restrict__ A, const unsigned short* __restrict__ W,
    const float* __restrict__ bias, void* __restrict__ C,
    int N, int K, int bx, int by,
    unsigned short* sA, unsigned short* sB)
{
    const int tid  = threadIdx.x;
    const int wave = tid >> 6, lane = tid & 63;
    const int quad = lane >> 4, l15 = lane & 15;
    const int TM = MT * 32;
    const int m0 = by * TM, n0 = bx * 128;
    const int wm = (wave & 1) * (MT * 16), wn = (wave >> 1) * 64;

    f32x4 acc[MT][4] = {};

    for (int k0 = 0; k0 < K; k0 += 64) {
        __syncthreads();                      // prev iteration's LDS reads done
        #pragma unroll
        for (int i = 0; i < MT; i++) {        // A: TM rows x 8 chunks
            int c   = tid + 256 * i;
            int row = c >> 3;
            int gk  = ((c & 7) ^ (row & 7)) * 8;
            int sb  = (wave * 64 + 256 * i) * 8;
            async16(&A[(size_t)(m0 + row) * K + k0 + gk], sA + sb);
        }
        #pragma unroll
        for (int i = 0; i < 4; i++) {         // B: 128 rows x 8 chunks
            int c   = tid + 256 * i;
            int row = c >> 3;
            int gk  = ((c & 7) ^ (row & 7)) * 8;
            int sb  = (wave * 64 + 256 * i) * 8;
            async16(&W[(size_t)(n0 + row) * K + k0 + gk], sB + sb);
        }
        __syncthreads();                      // drains vmcnt(0): data landed
        const int sw = l15 & 7;
        #pragma unroll
        for (int ks = 0; ks < 2; ks++) {
            bf16x8 af[MT], bfv[4];
            #pragma unroll
            for (int mt = 0; mt < MT; mt++)
                af[mt] = *(const bf16x8*)&sA[(wm + mt * 16 + l15) * 64 +
                                             (((ks * 4 + quad) ^ sw) * 8)];
            #pragma unroll
            for (int nt = 0; nt < 4; nt++)
                bfv[nt] = *(const bf16x8*)&sB[(wn + nt * 16 + l15) * 64 +
                                              (((ks * 4 + quad) ^ sw) * 8)];
            #pragma unroll
            for (int mt = 0; mt < MT; mt++)
                #pragma unroll
                for (int nt = 0; nt < 4; nt++)
                    acc[mt][nt] = __builtin_amdgcn_mfma_f32_16x16x32_bf16(
                        af[mt], bfv[nt], acc[mt][nt], 0, 0, 0);
        }
    }

    if (C_MODE == 2) {
        #pragma unroll
        for (int mt = 0; mt < MT; mt++) {
            #pragma unroll
            for (int r = 0; r < 4; r++) {
                int m = m0 + wm + mt * 16 + quad * 4 + r;
                float bm = bias[m];
                #pragma unroll
                for (int nt = 0; nt < 4; nt++) {
                    int n = n0 + wn + nt * 16 + l15;
                    int bb = n >> 11, t = n & 2047;
                    ((unsigned short*)C)[((size_t)bb * 1024 + m) * 2048 + t] =
                        f2bf(acc[mt][nt][r] + bm);
                }
            }
        }
    } else {
        #pragma unroll
        for (int nt = 0; nt < 4; nt++) {
            int n = n0 + wn + nt * 16 + l15;
            float bv = bias[n];
            #pragma unroll
            for (int mt = 0; mt < MT; mt++) {
                #pragma unroll
                for (int r = 0; r < 4; r++) {
                    int m = m0 + wm + mt * 16 + quad * 4 + r;   // D row = quad*4+reg
                    float val = acc[mt][nt][r] + bv;
                    if (C_MODE == 1) ((float*)C)[(size_t)m * N + n] = val;
                    else ((unsigned short*)C)[(size_t)m * N + n] = f2bf(val);
                }
            }
        }
    }
}

// Q,K,V projections + V-transpose batched: grid (256,1,3) = 768 blocks (~3/CU).
__global__ __launch_bounds__(256) void gemm_qkv(
    const unsigned short* __restrict__ Qb, const unsigned short* __restrict__ Kb,
    const unsigned short* __restrict__ Vb,
    const unsigned short* __restrict__ Wqb, const unsigned short* __restrict__ Wkb,
    const unsigned short* __restrict__ Wvb,
    const float* __restrict__ bq, const float* __restrict__ bk, const float* __restrict__ bv,
    unsigned short* __restrict__ Qp, unsigned short* __restrict__ Kp,
    unsigned short* __restrict__ Vt)
{
    __shared__ __align__(16) unsigned short sA[128 * 64];
    __shared__ __align__(16) unsigned short sB[128 * 64];
    const int z = blockIdx.z, id = blockIdx.x;
    if (z < 2) {
        gemm_core<0, 4>(z ? Kb : Qb, z ? Wkb : Wqb, z ? bk : bq, z ? Kp : Qp,
                        DMODEL, DMODEL, id & 7, id >> 3, sA, sB);
    } else {
        gemm_core<2, 4>(Wvb, Vb, bv, Vt, M_ROWS, DMODEL, id & 31, id >> 5, sA, sB);
    }
}

// Output projection: 64x128 tiles -> 512 blocks (2/CU hides the barrier drain).
__global__ __launch_bounds__(256) void gemm_o(
    const unsigned short* __restrict__ AO, const unsigned short* __restrict__ Wob,
    const float* __restrict__ bo, float* __restrict__ out)
{
    __shared__ __align__(16) unsigned short sA[64 * 64];
    __shared__ __align__(16) unsigned short sB[128 * 64];
    const int id = blockIdx.x;
    gemm_core<1, 2>(AO, Wob, bo, out, DMODEL, DMODEL, id & 7, id >> 3, sA, sB);
}

// ---------------- flash attention: 2-phase double-buffered, 32 q-rows/wave ----------------
// Round-4 post-mortem: the mt=2 restructure did NOT cut LDS traffic — K/V fragment
// reads sat inside the mt loop with intervening sPw ds_writes, so the compiler
// re-issued them (40 KB/wave-iter, same 2.62 GB total as before) and we only paid
// the occupancy cost. This round hoists kf/vf into registers ONCE per nt and
// shares them across both M-tiles: 24 KB/wave-iter, 1.57 GB total (-40%).
// Same grid 512 / 4 waves / double-buffer / 1 barrier per tile as round 4.
#define QBLK 128
#define KVB 64
#define AW 4          // waves per attn block

__global__ __launch_bounds__(256) void attn_kernel(
    const unsigned short* __restrict__ Qp,
    const unsigned short* __restrict__ Kp,
    const unsigned short* __restrict__ Vt,
    const int* __restrict__ maskp,     // [B,T], nonzero = keep
    unsigned short* __restrict__ Op)
{
    __shared__ __align__(16) unsigned short sK[2][KVB * 64];    // [s][d], swizzled
    __shared__ __align__(16) unsigned short sV[2][KVB * 64];    // [d][s], swizzled
    __shared__ __align__(16) unsigned short sP[AW * 32 * LDT];  // per-wave P [q][s], padded
    __shared__ float smf[T_SEQ];                                // 0 or -30000 per key col

    const int tid  = threadIdx.x;
    const int wave = tid >> 6, lane = tid & 63;
    const int quad = lane >> 4, l15 = lane & 15;
    const int qblk = blockIdx.x, h = blockIdx.y, b = blockIdx.z;

    const float SCL2 = 0.125f * 1.44269504089f;   // 1/sqrt(DK) * log2(e)
    const float MNEG = -30000.f;                  // exp2(-30000+x) == 0

    // Q fragments for both M-tiles (rows wave*32 + mt*16 + l15)
    bf16x8 aq[2][2];
    #pragma unroll
    for (int mt = 0; mt < 2; mt++) {
        const int qrow = qblk * QBLK + wave * 32 + mt * 16 + l15;
        const unsigned short* qptr =
            Qp + (size_t)(b * T_SEQ + qrow) * DMODEL + h * DKH + quad * 8;
        aq[mt][0] = *(const bf16x8*)qptr;
        aq[mt][1] = *(const bf16x8*)(qptr + 32);
    }

    const unsigned short* Kb_ = Kp + (size_t)b * T_SEQ * DMODEL + h * DKH;
    const unsigned short* VtB = Vt + ((size_t)b * DMODEL + h * DKH) * T_SEQ;

    f32x4 O[2][4] = {};
    float l_r[2][4] = {};
    unsigned short* sPw = sP + wave * 32 * LDT;

    // prologue: stage tile 0 (512 chunks of 16B over 256 threads), expand mask
    #pragma unroll
    for (int i = 0; i < 2; i++) {
        int c   = tid + 256 * i;
        int row = c >> 3;
        int gk  = ((c & 7) ^ (row & 7)) * 8;   // swizzled global chunk
        int sb  = (wave * 64 + 256 * i) * 8;   // wave-uniform LDS base (elems)
        async16(&Kb_[(size_t)row * DMODEL + gk], &sK[0][sb]);
        async16(&VtB[(size_t)row * T_SEQ + gk], &sV[0][sb]);
    }
    #pragma unroll
    for (int j = 0; j < 8; j++) {
        int i = tid + 256 * j;
        smf[i] = maskp[b * T_SEQ + i] ? 0.f : MNEG;
    }
    __syncthreads();    // drains tile-0 stage + mask writes

    const int sw = l15 & 7;
    for (int t = 0; t < T_SEQ / KVB; ++t) {
        const int cur = t & 1;
        const int s0 = t * KVB;
        // ---- prefetch tile t+1 into the other buffer (overlaps this tile's compute)
        if (t + 1 < T_SEQ / KVB) {
            #pragma unroll
            for (int i = 0; i < 2; i++) {
                int c   = tid + 256 * i;
                int row = c >> 3;
                int gk  = ((c & 7) ^ (row & 7)) * 8;
                int sb  = (wave * 64 + 256 * i) * 8;
                async16(&Kb_[(size_t)(s0 + KVB + row) * DMODEL + gk], &sK[cur ^ 1][sb]);
                async16(&VtB[(size_t)row * T_SEQ + s0 + KVB + gk], &sV[cur ^ 1][sb]);
            }
        }

        // ---- S = Q K^T for BOTH M-tiles, K-fragments hoisted (read once) ----
        f32x4 S[2][4];
        __builtin_amdgcn_s_setprio(1);
        #pragma unroll
        for (int nt = 0; nt < 4; nt++) {
            const unsigned short* kr = &sK[cur][(nt * 16 + l15) * 64];
            const bf16x8 kf0 = *(const bf16x8*)&kr[(quad ^ sw) * 8];
            const bf16x8 kf1 = *(const bf16x8*)&kr[((quad + 4) ^ sw) * 8];
            #pragma unroll
            for (int mt = 0; mt < 2; mt++) {
                f32x4 z = {};
                z = __builtin_amdgcn_mfma_f32_16x16x32_bf16(aq[mt][0], kf0, z, 0, 0, 0);
                z = __builtin_amdgcn_mfma_f32_16x16x32_bf16(aq[mt][1], kf1, z, 0, 0, 0);
                S[mt][nt] = z;
            }
        }
        __builtin_amdgcn_s_setprio(0);

        // ---- p = exp2(s*c + madd); no max, no shuffles ----
        #pragma unroll
        for (int mt = 0; mt < 2; mt++) {
            #pragma unroll
            for (int nt = 0; nt < 4; nt++) {
                float madd = smf[s0 + nt * 16 + l15];
                #pragma unroll
                for (int r = 0; r < 4; r++) {
                    float p = __builtin_amdgcn_exp2f(fmaf(S[mt][nt][r], SCL2, madd));
                    l_r[mt][r] += p;
                    unsigned u = __builtin_bit_cast(unsigned, p) + 0x8000u;  // round-half-up
                    sPw[(mt * 16 + quad * 4 + r) * LDT + nt * 16 + l15] =
                        (unsigned short)(u >> 16);
                }
            }
        }
        // NO barrier: sPw is per-wave private; intra-wave ds ordering via lgkmcnt.

        // ---- O += P V  (A = P rows, B = V^T rows), V-fragments hoisted ----
        bf16x8 ap0[2], ap1[2];
        #pragma unroll
        for (int mt = 0; mt < 2; mt++) {
            ap0[mt] = *(const bf16x8*)&sPw[(mt * 16 + l15) * LDT + quad * 8];
            ap1[mt] = *(const bf16x8*)&sPw[(mt * 16 + l15) * LDT + 32 + quad * 8];
        }
        __builtin_amdgcn_s_setprio(1);
        #pragma unroll
        for (int nt = 0; nt < 4; nt++) {
            const unsigned short* vr = &sV[cur][(nt * 16 + l15) * 64];
            const bf16x8 vf0 = *(const bf16x8*)&vr[(quad ^ sw) * 8];
            const bf16x8 vf1 = *(const bf16x8*)&vr[((quad + 4) ^ sw) * 8];
            #pragma unroll
            for (int mt = 0; mt < 2; mt++) {
                O[mt][nt] = __builtin_amdgcn_mfma_f32_16x16x32_bf16(
                    ap0[mt], vf0, O[mt][nt], 0, 0, 0);
                O[mt][nt] = __builtin_amdgcn_mfma_f32_16x16x32_bf16(
                    ap1[mt], vf1, O[mt][nt], 0, 0, 0);
            }
        }
        __builtin_amdgcn_s_setprio(0);

        // single barrier: drains prefetch (vmcnt->0) AND guarantees all waves
        // finished reading buf[cur] before iteration t+1 overwrites it.
        __syncthreads();
    }

    // ---- row-sum reduce, normalize, write AO [B,T,D] ----
    #pragma unroll
    for (int mt = 0; mt < 2; mt++) {
        #pragma unroll
        for (int r = 0; r < 4; r++) {
            float l = l_r[mt][r];
            l += __shfl_xor(l, 1);
            l += __shfl_xor(l, 2);
            l += __shfl_xor(l, 4);
            l += __shfl_xor(l, 8);
            l_r[mt][r] = 1.0f / fmaxf(l, 1e-30f);
        }
        #pragma unroll
        for (int nt = 0; nt < 4; nt++) {
            #pragma unroll
            for (int r = 0; r < 4; r++) {
                int q = qblk * QBLK + wave * 32 + mt * 16 + quad * 4 + r;
                Op[(size_t)(b * T_SEQ + q) * DMODEL + h * DKH + nt * 16 + l15] =
                    f2bf(O[mt][nt][r] * l_r[mt][r]);
            }
        }
    }
}

// ---------------- legacy fp32-staging GEMM (fallback path only) ----------------
template<int A_BF16, int W_BF16, int C_MODE>
__global__ __launch_bounds__(256) void gemm_bt_cvt(
    const void* __restrict__ A_, const void* __restrict__ W_,
    const float* __restrict__ bias, void* __restrict__ C_,
    int M, int N, int K)
{
    __shared__ __align__(16) unsigned short sA[128 * LDT];
    __shared__ __align__(16) unsigned short sB[128 * LDT];
    const int tid  = threadIdx.x;
    const int wave = tid >> 6, lane = tid & 63;
    const int quad = lane >> 4, l15 = lane & 15;
    const int m0 = blockIdx.y * 128, n0 = blockIdx.x * 128;
    const int wm = (wave & 1) * 64, wn = (wave >> 1) * 64;
    f32x4 acc[4][4] = {};
    for (int k0 = 0; k0 < K; k0 += 64) {
        __syncthreads();
        #pragma unroll
        for (int i = 0; i < 4; i++) {
            int c = tid + 256 * i;
            int row = c >> 3, koff = (c & 7) * 8;
            if (A_BF16)
                *(uint4*)&sA[row * LDT + koff] =
                    *(const uint4*)&((const unsigned short*)A_)[(size_t)(m0 + row) * K + k0 + koff];
            else
                *(uint4*)&sA[row * LDT + koff] =
                    cvt8((const float*)A_ + (size_t)(m0 + row) * K + k0 + koff);
            if (W_BF16)
                *(uint4*)&sB[row * LDT + koff] =
                    *(const uint4*)&((const unsigned short*)W_)[(size_t)(n0 + row) * K + k0 + koff];
            else
                *(uint4*)&sB[row * LDT + koff] =
                    cvt8((const float*)W_ + (size_t)(n0 + row) * K + k0 + koff);
        }
        __syncthreads();
        #pragma unroll
        for (int ks = 0; ks < 2; ks++) {
            bf16x8 af[4], bfr[4];
            #pragma unroll
            for (int mt = 0; mt < 4; mt++)
                af[mt] = *(const bf16x8*)&sA[(wm + mt * 16 + l15) * LDT + ks * 32 + quad * 8];
            #pragma unroll
            for (int nt = 0; nt < 4; nt++)
                bfr[nt] = *(const bf16x8*)&sB[(wn + nt * 16 + l15) * LDT + ks * 32 + quad * 8];
            #pragma unroll
            for (int mt = 0; mt < 4; mt++)
                #pragma unroll
                for (int nt = 0; nt < 4; nt++)
                    acc[mt][nt] = __builtin_amdgcn_mfma_f32_16x16x32_bf16(
                        af[mt], bfr[nt], acc[mt][nt], 0, 0, 0);
        }
    }
    if (C_MODE == 2) {
        #pragma unroll
        for (int mt = 0; mt < 4; mt++)
            #pragma unroll
            for (int r = 0; r < 4; r++) {
                int m = m0 + wm + mt * 16 + quad * 4 + r;
                float bm = bias[m];
                #pragma unroll
                for (int nt = 0; nt < 4; nt++) {
                    int n = n0 + wn + nt * 16 + l15;
                    int bb = n >> 11, t = n & 2047;
                    ((unsigned short*)C_)[((size_t)bb * 1024 + m) * 2048 + t] =
                        f2bf(acc[mt][nt][r] + bm);
                }
            }
    } else {
        #pragma unroll
        for (int nt = 0; nt < 4; nt++) {
            int n = n0 + wn + nt * 16 + l15;
            float bv = bias[n];
            #pragma unroll
            for (int mt = 0; mt < 4; mt++)
                #pragma unroll
                for (int r = 0; r < 4; r++) {
                    int m = m0 + wm + mt * 16 + quad * 4 + r;
                    float val = acc[mt][nt][r] + bv;
                    if (C_MODE == 1) ((float*)C_)[(size_t)m * N + n] = val;
                    else ((unsigned short*)C_)[(size_t)m * N + n] = f2bf(val);
                }
        }
    }
}

extern "C" void kernel_launch(void* const* d_in, const int* in_sizes, int n_in,
                              void* d_out, int out_size, void* d_ws, size_t ws_size,
                              hipStream_t stream)
{
    const float* q  = (const float*)d_in[0];
    const float* k  = (const float*)d_in[1];
    const float* v  = (const float*)d_in[2];
    const int*   mk = (const int*)d_in[3];
    const float* Wq = (const float*)d_in[4];
    const float* bq = (const float*)d_in[5];
    const float* Wk = (const float*)d_in[6];
    const float* bk = (const float*)d_in[7];
    const float* Wv = (const float*)d_in[8];
    const float* bv = (const float*)d_in[9];
    const float* Wo = (const float*)d_in[10];
    const float* bo = (const float*)d_in[11];
    float* out = (float*)d_out;

    unsigned short* wsb = (unsigned short*)d_ws;
    const dim3 gA(T_SEQ / QBLK, NHEAD, B_SZ);   // 16 x 16 x 2 = 512 blocks

    if (ws_size >= (size_t)64 * 1024 * 1024) {
        // Path A: pre-convert to bf16; m97-style global_load_lds GEMMs.
        unsigned short* Qb  = wsb;
        unsigned short* Kb  = wsb + INP_E;
        unsigned short* Vb  = wsb + 2 * INP_E;
        unsigned short* Wqb = wsb + 3 * INP_E;
        unsigned short* Wkb = wsb + 3 * INP_E + W_E;
        unsigned short* Wvb = wsb + 3 * INP_E + 2 * W_E;
        unsigned short* Wob = wsb + 3 * INP_E + 3 * W_E;
        unsigned short* Qp  = wsb + 4 * INP_E;
        unsigned short* Kp  = wsb + 5 * INP_E;
        unsigned short* Vt  = wsb + 6 * INP_E;
        unsigned short* AO  = wsb + 7 * INP_E;       // end = 64MB

        cvt_all<<<8192, 256, 0, stream>>>(q, k, v, Wq, Wk, Wv, Wo, wsb);
        gemm_qkv<<<dim3(256, 1, 3), 256, 0, stream>>>(
            Qb, Kb, Vb, Wqb, Wkb, Wvb, bq, bk, bv, Qp, Kp, Vt);
        attn_kernel<<<gA, 256, 0, stream>>>(Qp, Kp, Vt, mk, AO);
        gemm_o<<<dim3(512, 1, 1), 256, 0, stream>>>(AO, Wob, bo, out);
    } else {
        // Path C fallback: in-GEMM convert (32MB ws), legacy kernels.
        unsigned short* Qp = wsb;
        unsigned short* Kp = wsb + INP_E;
        unsigned short* Vt = wsb + 2 * INP_E;
        unsigned short* AO = wsb + 3 * INP_E;
        const dim3 gN(DMODEL / 128, M_ROWS / 128);
        const dim3 gV(M_ROWS / 128, DMODEL / 128);
        gemm_bt_cvt<0, 0, 0><<<gN, 256, 0, stream>>>(q, Wq, bq, Qp, M_ROWS, DMODEL, DMODEL);
        gemm_bt_cvt<0, 0, 0><<<gN, 256, 0, stream>>>(k, Wk, bk, Kp, M_ROWS, DMODEL, DMODEL);
        gemm_bt_cvt<0, 0, 2><<<gV, 256, 0, stream>>>(Wv, v, bv, Vt, DMODEL, M_ROWS, DMODEL);
        attn_kernel<<<gA, 256, 0, stream>>>(Qp, Kp, Vt, mk, AO);
        gemm_bt_cvt<1, 0, 1><<<gN, 256, 0, stream>>>(AO, Wo, bo, out, M_ROWS, DMODEL, DMODEL);
    }
}

// Round 6
// 231.874 us; speedup vs baseline: 1.0705x; 1.0261x over previous
//
#include <hip/hip_runtime.h>
#include <stdint.h>

// Problem constants (B,T,D,H fixed by the reference)
#define B_SZ 2
#define T_SEQ 2048
#define DMODEL 1024
#define NHEAD 16
#define DKH 64
#define M_ROWS (B_SZ * T_SEQ)   // 4096

#define LDT 72    // padded LDS row stride (bf16) for VALU-written tiles (sP): 2-way = free

#define INP_E  4194304u   // 4M elems per input tensor
#define W_E    1048576u   // 1M elems per weight

typedef __bf16 bf16x8 __attribute__((ext_vector_type(8)));
typedef float  f32x4  __attribute__((ext_vector_type(4)));

__device__ __forceinline__ unsigned short f2bf(float f) {
    unsigned u = __builtin_bit_cast(unsigned, f);
    u += 0x7fffu + ((u >> 16) & 1u);   // RNE
    return (unsigned short)(u >> 16);
}
// 8 consecutive fp32 -> 8 bf16 packed in a uint4
__device__ __forceinline__ uint4 cvt8(const float* p) {
    float4 f0 = *(const float4*)p, f1 = *(const float4*)(p + 4);
    uint4 r;
    r.x = (unsigned)f2bf(f0.x) | ((unsigned)f2bf(f0.y) << 16);
    r.y = (unsigned)f2bf(f0.z) | ((unsigned)f2bf(f0.w) << 16);
    r.z = (unsigned)f2bf(f1.x) | ((unsigned)f2bf(f1.y) << 16);
    r.w = (unsigned)f2bf(f1.z) | ((unsigned)f2bf(f1.w) << 16);
    return r;
}

// Async global->LDS, 16B per lane. LDS dest = wave-uniform base + lane*16 (m104/m108).
__device__ __forceinline__ void async16(const unsigned short* g, unsigned short* l) {
    __builtin_amdgcn_global_load_lds(
        (const __attribute__((address_space(1))) void*)g,
        (__attribute__((address_space(3))) void*)l, 16, 0, 0);
}

// One-shot fp32 -> bf16 conversion of q,k,v + 4 weights into ws.
__global__ __launch_bounds__(256) void cvt_all(
    const float* __restrict__ q, const float* __restrict__ k, const float* __restrict__ v,
    const float* __restrict__ wq, const float* __restrict__ wk,
    const float* __restrict__ wv, const float* __restrict__ wo,
    unsigned short* __restrict__ wsb)
{
    int blk = blockIdx.x;
    const float* src; unsigned short* dst; int lb;
    if      (blk < 2048) { src = q;  dst = wsb;                       lb = blk; }
    else if (blk < 4096) { src = k;  dst = wsb + INP_E;               lb = blk - 2048; }
    else if (blk < 6144) { src = v;  dst = wsb + 2 * INP_E;           lb = blk - 4096; }
    else if (blk < 6656) { src = wq; dst = wsb + 3 * INP_E;           lb = blk - 6144; }
    else if (blk < 7168) { src = wk; dst = wsb + 3 * INP_E + W_E;     lb = blk - 6656; }
    else if (blk < 7680) { src = wv; dst = wsb + 3 * INP_E + 2 * W_E; lb = blk - 7168; }
    else                 { src = wo; dst = wsb + 3 * INP_E + 3 * W_E; lb = blk - 7680; }
    size_t i = ((size_t)lb * 256 + threadIdx.x) * 8;
    *(uint4*)&dst[i] = cvt8(src + i);
}

// ---------------- m97-style GEMM core ----------------
// D[m][n] = sum_k A[m][k]*W[n][k] + bias. Tile (MT*32) x 128, BK=64,
// global_load_lds width=16 into UNPADDED stride-64 LDS with XOR column-chunk
// swizzle (LDS[row][j] holds global chunk j^(row&7); reads un-swizzle).
// C_MODE: 0 = bf16 C[m*N+n] (bias[n]); 1 = fp32 C (bias[n]);
//         2 = Vt[(b*1024+m)*2048 + t] (bias[m], transposed store).
template<int C_MODE, int MT>
__device__ __forceinline__ void gemm_core(
    const unsigned short* __restrict__ A, const unsigned short* __restrict__ W,
    const float* __restrict__ bias, void* __restrict__ C,
    int N, int K, int bx, int by,
    unsigned short* sA, unsigned short* sB)
{
    const int tid  = threadIdx.x;
    const int wave = tid >> 6, lane = tid & 63;
    const int quad = lane >> 4, l15 = lane & 15;
    const int TM = MT * 32;
    const int m0 = by * TM, n0 = bx * 128;
    const int wm = (wave & 1) * (MT * 16), wn = (wave >> 1) * 64;

    f32x4 acc[MT][4] = {};

    for (int k0 = 0; k0 < K; k0 += 64) {
        __syncthreads();                      // prev iteration's LDS reads done
        #pragma unroll
        for (int i = 0; i < MT; i++) {        // A: TM rows x 8 chunks
            int c   = tid + 256 * i;
            int row = c >> 3;
            int gk  = ((c & 7) ^ (row & 7)) * 8;
            int sb  = (wave * 64 + 256 * i) * 8;
            async16(&A[(size_t)(m0 + row) * K + k0 + gk], sA + sb);
        }
        #pragma unroll
        for (int i = 0; i < 4; i++) {         // B: 128 rows x 8 chunks
            int c   = tid + 256 * i;
            int row = c >> 3;
            int gk  = ((c & 7) ^ (row & 7)) * 8;
            int sb  = (wave * 64 + 256 * i) * 8;
            async16(&W[(size_t)(n0 + row) * K + k0 + gk], sB + sb);
        }
        __syncthreads();                      // drains vmcnt(0): data landed
        const int sw = l15 & 7;
        #pragma unroll
        for (int ks = 0; ks < 2; ks++) {
            bf16x8 af[MT], bfv[4];
            #pragma unroll
            for (int mt = 0; mt < MT; mt++)
                af[mt] = *(const bf16x8*)&sA[(wm + mt * 16 + l15) * 64 +
                                             (((ks * 4 + quad) ^ sw) * 8)];
            #pragma unroll
            for (int nt = 0; nt < 4; nt++)
                bfv[nt] = *(const bf16x8*)&sB[(wn + nt * 16 + l15) * 64 +
                                              (((ks * 4 + quad) ^ sw) * 8)];
            #pragma unroll
            for (int mt = 0; mt < MT; mt++)
                #pragma unroll
                for (int nt = 0; nt < 4; nt++)
                    acc[mt][nt] = __builtin_amdgcn_mfma_f32_16x16x32_bf16(
                        af[mt], bfv[nt], acc[mt][nt], 0, 0, 0);
        }
    }

    if (C_MODE == 2) {
        #pragma unroll
        for (int mt = 0; mt < MT; mt++) {
            #pragma unroll
            for (int r = 0; r < 4; r++) {
                int m = m0 + wm + mt * 16 + quad * 4 + r;
                float bm = bias[m];
                #pragma unroll
                for (int nt = 0; nt < 4; nt++) {
                    int n = n0 + wn + nt * 16 + l15;
                    int bb = n >> 11, t = n & 2047;
                    ((unsigned short*)C)[((size_t)bb * 1024 + m) * 2048 + t] =
                        f2bf(acc[mt][nt][r] + bm);
                }
            }
        }
    } else {
        #pragma unroll
        for (int nt = 0; nt < 4; nt++) {
            int n = n0 + wn + nt * 16 + l15;
            float bv = bias[n];
            #pragma unroll
            for (int mt = 0; mt < MT; mt++) {
                #pragma unroll
                for (int r = 0; r < 4; r++) {
                    int m = m0 + wm + mt * 16 + quad * 4 + r;   // D row = quad*4+reg
                    float val = acc[mt][nt][r] + bv;
                    if (C_MODE == 1) ((float*)C)[(size_t)m * N + n] = val;
                    else ((unsigned short*)C)[(size_t)m * N + n] = f2bf(val);
                }
            }
        }
    }
}

// Q,K,V projections + V-transpose batched: grid (256,1,3) = 768 blocks (~3/CU).
__global__ __launch_bounds__(256) void gemm_qkv(
    const unsigned short* __restrict__ Qb, const unsigned short* __restrict__ Kb,
    const unsigned short* __restrict__ Vb,
    const unsigned short* __restrict__ Wqb, const unsigned short* __restrict__ Wkb,
    const unsigned short* __restrict__ Wvb,
    const float* __restrict__ bq, const float* __restrict__ bk, const float* __restrict__ bv,
    unsigned short* __restrict__ Qp, unsigned short* __restrict__ Kp,
    unsigned short* __restrict__ Vt)
{
    __shared__ __align__(16) unsigned short sA[128 * 64];
    __shared__ __align__(16) unsigned short sB[128 * 64];
    const int z = blockIdx.z, id = blockIdx.x;
    if (z < 2) {
        gemm_core<0, 4>(z ? Kb : Qb, z ? Wkb : Wqb, z ? bk : bq, z ? Kp : Qp,
                        DMODEL, DMODEL, id & 7, id >> 3, sA, sB);
    } else {
        gemm_core<2, 4>(Wvb, Vb, bv, Vt, M_ROWS, DMODEL, id & 31, id >> 5, sA, sB);
    }
}

// Output projection: 64x128 tiles -> 512 blocks (2/CU hides the barrier drain).
__global__ __launch_bounds__(256) void gemm_o(
    const unsigned short* __restrict__ AO, const unsigned short* __restrict__ Wob,
    const float* __restrict__ bo, float* __restrict__ out)
{
    __shared__ __align__(16) unsigned short sA[64 * 64];
    __shared__ __align__(16) unsigned short sB[128 * 64];
    const int id = blockIdx.x;
    gemm_core<1, 2>(AO, Wob, bo, out, DMODEL, DMODEL, id & 7, id >> 3, sA, sB);
}

// ---------------- flash attention: intra-block KV split, 16 waves/CU ----------------
// Round-5 post-mortem: R=32 + hoisting cut LDS traffic to 1.57 GB but at 8 waves/CU
// the softmax VALU chain (~1100cy/wave-iter) and LDS pipe serialize within each wave
// (VALUBusy 47%, time 71us). Need R=32 traffic AND 16 waves/CU together.
// This round: 512 threads / 8 waves; waves 0-3 (group 0) and 4-7 (group 1) own the
// SAME 128 q-rows (32 rows/wave) but EVEN vs ODD KV tiles — valid because this
// no-max softmax is linear in keys (O, l are pure sums). Each round stages two
// tiles (single-buffered, 2 barriers; cross-block overlap at 2 blocks/CU hides the
// stage). Final merge of the two groups' partial O/l goes through the dead K/V LDS
// — no global partials. LDS 77 KB -> 2 blocks/CU -> 16 waves/CU, traffic 1.57 GB.
#define QBLK 128
#define KVB 64

__global__ __launch_bounds__(512, 4) void attn_kernel(
    const unsigned short* __restrict__ Qp,
    const unsigned short* __restrict__ Kp,
    const unsigned short* __restrict__ Vt,
    const int* __restrict__ maskp,     // [B,T], nonzero = keep
    unsigned short* __restrict__ Op)
{
    // [K/V][tile 0|1][64x64] — tile g is computed by wave-group g this round
    __shared__ __align__(16) unsigned short sKV[2][2][KVB * 64];
    __shared__ __align__(16) unsigned short sP[8 * 32 * LDT];   // per-wave P [q][s]
    __shared__ float smf[T_SEQ];                                // 0 or -30000 per key col

    const int tid  = threadIdx.x;
    const int wave = tid >> 6, lane = tid & 63;
    const int g    = wave >> 2, wl = wave & 3;
    const int quad = lane >> 4, l15 = lane & 15;
    const int qblk = blockIdx.x, h = blockIdx.y, b = blockIdx.z;

    const float SCL2 = 0.125f * 1.44269504089f;   // 1/sqrt(DK) * log2(e)
    const float MNEG = -30000.f;                  // exp2(-30000+x) == 0

    // Q fragments for both M-tiles (rows wl*32 + mt*16 + l15); same for both groups
    bf16x8 aq[2][2];
    #pragma unroll
    for (int mt = 0; mt < 2; mt++) {
        const int qrow = qblk * QBLK + wl * 32 + mt * 16 + l15;
        const unsigned short* qptr =
            Qp + (size_t)(b * T_SEQ + qrow) * DMODEL + h * DKH + quad * 8;
        aq[mt][0] = *(const bf16x8*)qptr;
        aq[mt][1] = *(const bf16x8*)(qptr + 32);
    }

    const unsigned short* Kb_ = Kp + (size_t)b * T_SEQ * DMODEL + h * DKH;
    const unsigned short* VtB = Vt + ((size_t)b * DMODEL + h * DKH) * T_SEQ;

    f32x4 O[2][4] = {};
    float l_r[2][4] = {};
    unsigned short* sPw = sP + wave * 32 * LDT;

    // expand mask once (covered by round-0's post-stage barrier)
    #pragma unroll
    for (int j = 0; j < 4; j++) {
        int i = tid + 512 * j;
        smf[i] = maskp[b * T_SEQ + i] ? 0.f : MNEG;
    }

    const int sw = l15 & 7;
    for (int rr = 0; rr < T_SEQ / (2 * KVB); ++rr) {   // 16 rounds, 2 tiles each
        // ---- stage tiles 2rr (buf 0) and 2rr+1 (buf 1): 2048 x 16B chunks over 512 thr
        #pragma unroll
        for (int i = 0; i < 2; i++) {
            int c    = tid + 512 * i;          // K chunk id 0..1023
            int tile = c >> 9, cc = c & 511;
            int row  = cc >> 3;
            int gk   = ((cc & 7) ^ (row & 7)) * 8;
            int sb   = (wave * 64 + 512 * i) * 8;   // wave-uniform LDS base (elems)
            int key0 = rr * 128 + tile * 64;
            async16(&Kb_[(size_t)(key0 + row) * DMODEL + gk], &sKV[0][0][0] + sb);
            async16(&VtB[(size_t)row * T_SEQ + key0 + gk], &sKV[1][0][0] + sb);
        }
        __syncthreads();   // drains vmcnt: both tiles landed (and smf on round 0)

        const unsigned short* sKp = &sKV[0][g][0];
        const unsigned short* sVp = &sKV[1][g][0];
        const int s0 = (2 * rr + g) * KVB;

        // ---- S = Q K^T for both M-tiles, K-fragments hoisted (read once) ----
        f32x4 S[2][4];
        __builtin_amdgcn_s_setprio(1);
        #pragma unroll
        for (int nt = 0; nt < 4; nt++) {
            const unsigned short* kr = &sKp[(nt * 16 + l15) * 64];
            const bf16x8 kf0 = *(const bf16x8*)&kr[(quad ^ sw) * 8];
            const bf16x8 kf1 = *(const bf16x8*)&kr[((quad + 4) ^ sw) * 8];
            #pragma unroll
            for (int mt = 0; mt < 2; mt++) {
                f32x4 z = {};
                z = __builtin_amdgcn_mfma_f32_16x16x32_bf16(aq[mt][0], kf0, z, 0, 0, 0);
                z = __builtin_amdgcn_mfma_f32_16x16x32_bf16(aq[mt][1], kf1, z, 0, 0, 0);
                S[mt][nt] = z;
            }
        }
        __builtin_amdgcn_s_setprio(0);

        // ---- p = exp2(s*c + madd); no max, no shuffles ----
        #pragma unroll
        for (int mt = 0; mt < 2; mt++) {
            #pragma unroll
            for (int nt = 0; nt < 4; nt++) {
                float madd = smf[s0 + nt * 16 + l15];
                #pragma unroll
                for (int r = 0; r < 4; r++) {
                    float p = __builtin_amdgcn_exp2f(fmaf(S[mt][nt][r], SCL2, madd));
                    l_r[mt][r] += p;
                    unsigned u = __builtin_bit_cast(unsigned, p) + 0x8000u;  // round-half-up
                    sPw[(mt * 16 + quad * 4 + r) * LDT + nt * 16 + l15] =
                        (unsigned short)(u >> 16);
                }
            }
        }
        // NO barrier: sPw is per-wave private; intra-wave ds ordering via lgkmcnt.

        // ---- O += P V  (A = P rows, B = V^T rows), V-fragments hoisted ----
        bf16x8 ap0[2], ap1[2];
        #pragma unroll
        for (int mt = 0; mt < 2; mt++) {
            ap0[mt] = *(const bf16x8*)&sPw[(mt * 16 + l15) * LDT + quad * 8];
            ap1[mt] = *(const bf16x8*)&sPw[(mt * 16 + l15) * LDT + 32 + quad * 8];
        }
        __builtin_amdgcn_s_setprio(1);
        #pragma unroll
        for (int nt = 0; nt < 4; nt++) {
            const unsigned short* vr = &sVp[(nt * 16 + l15) * 64];
            const bf16x8 vf0 = *(const bf16x8*)&vr[(quad ^ sw) * 8];
            const bf16x8 vf1 = *(const bf16x8*)&vr[((quad + 4) ^ sw) * 8];
            #pragma unroll
            for (int mt = 0; mt < 2; mt++) {
                O[mt][nt] = __builtin_amdgcn_mfma_f32_16x16x32_bf16(
                    ap0[mt], vf0, O[mt][nt], 0, 0, 0);
                O[mt][nt] = __builtin_amdgcn_mfma_f32_16x16x32_bf16(
                    ap1[mt], vf1, O[mt][nt], 0, 0, 0);
            }
        }
        __builtin_amdgcn_s_setprio(0);

        __syncthreads();   // all reads of this round's tiles done before next stage
    }

    // ---- raw row-sums (sum over the 16 l15 lanes within each quad) ----
    #pragma unroll
    for (int mt = 0; mt < 2; mt++) {
        #pragma unroll
        for (int r = 0; r < 4; r++) {
            float l = l_r[mt][r];
            l += __shfl_xor(l, 1);
            l += __shfl_xor(l, 2);
            l += __shfl_xor(l, 4);
            l += __shfl_xor(l, 8);
            l_r[mt][r] = l;
        }
    }

    // ---- group merge via dead K/V LDS: g1 deposits partial O (f32) + l; g0 merges
    float* OM = (float*)&sKV[0][0][0];   // [128][64] f32 = 32 KB
    float* LM = (float*)sP;              // 128 f32
    if (g == 1) {
        #pragma unroll
        for (int mt = 0; mt < 2; mt++) {
            #pragma unroll
            for (int r = 0; r < 4; r++) {
                int row = wl * 32 + mt * 16 + quad * 4 + r;
                if (l15 == 0) LM[row] = l_r[mt][r];
                #pragma unroll
                for (int nt = 0; nt < 4; nt++)
                    OM[row * 64 + nt * 16 + l15] = O[mt][nt][r];
            }
        }
    }
    __syncthreads();
    if (g == 0) {
        #pragma unroll
        for (int mt = 0; mt < 2; mt++) {
            #pragma unroll
            for (int r = 0; r < 4; r++) {
                int row = wl * 32 + mt * 16 + quad * 4 + r;
                float inv = 1.0f / fmaxf(l_r[mt][r] + LM[row], 1e-30f);
                int q = qblk * QBLK + row;
                #pragma unroll
                for (int nt = 0; nt < 4; nt++) {
                    float val = (O[mt][nt][r] + OM[row * 64 + nt * 16 + l15]) * inv;
                    Op[(size_t)(b * T_SEQ + q) * DMODEL + h * DKH + nt * 16 + l15] =
                        f2bf(val);
                }
            }
        }
    }
}

// ---------------- legacy fp32-staging GEMM (fallback path only) ----------------
template<int A_BF16, int W_BF16, int C_MODE>
__global__ __launch_bounds__(256) void gemm_bt_cvt(
    const void* __restrict__ A_, const void* __restrict__ W_,
    const float* __restrict__ bias, void* __restrict__ C_,
    int M, int N, int K)
{
    __shared__ __align__(16) unsigned short sA[128 * LDT];
    __shared__ __align__(16) unsigned short sB[128 * LDT];
    const int tid  = threadIdx.x;
    const int wave = tid >> 6, lane = tid & 63;
    const int quad = lane >> 4, l15 = lane & 15;
    const int m0 = blockIdx.y * 128, n0 = blockIdx.x * 128;
    const int wm = (wave & 1) * 64, wn = (wave >> 1) * 64;
    f32x4 acc[4][4] = {};
    for (int k0 = 0; k0 < K; k0 += 64) {
        __syncthreads();
        #pragma unroll
        for (int i = 0; i < 4; i++) {
            int c = tid + 256 * i;
            int row = c >> 3, koff = (c & 7) * 8;
            if (A_BF16)
                *(uint4*)&sA[row * LDT + koff] =
                    *(const uint4*)&((const unsigned short*)A_)[(size_t)(m0 + row) * K + k0 + koff];
            else
                *(uint4*)&sA[row * LDT + koff] =
                    cvt8((const float*)A_ + (size_t)(m0 + row) * K + k0 + koff);
            if (W_BF16)
                *(uint4*)&sB[row * LDT + koff] =
                    *(const uint4*)&((const unsigned short*)W_)[(size_t)(n0 + row) * K + k0 + koff];
            else
                *(uint4*)&sB[row * LDT + koff] =
                    cvt8((const float*)W_ + (size_t)(n0 + row) * K + k0 + koff);
        }
        __syncthreads();
        #pragma unroll
        for (int ks = 0; ks < 2; ks++) {
            bf16x8 af[4], bfr[4];
            #pragma unroll
            for (int mt = 0; mt < 4; mt++)
                af[mt] = *(const bf16x8*)&sA[(wm + mt * 16 + l15) * LDT + ks * 32 + quad * 8];
            #pragma unroll
            for (int nt = 0; nt < 4; nt++)
                bfr[nt] = *(const bf16x8*)&sB[(wn + nt * 16 + l15) * LDT + ks * 32 + quad * 8];
            #pragma unroll
            for (int mt = 0; mt < 4; mt++)
                #pragma unroll
                for (int nt = 0; nt < 4; nt++)
                    acc[mt][nt] = __builtin_amdgcn_mfma_f32_16x16x32_bf16(
                        af[mt], bfr[nt], acc[mt][nt], 0, 0, 0);
        }
    }
    if (C_MODE == 2) {
        #pragma unroll
        for (int mt = 0; mt < 4; mt++)
            #pragma unroll
            for (int r = 0; r < 4; r++) {
                int m = m0 + wm + mt * 16 + quad * 4 + r;
                float bm = bias[m];
                #pragma unroll
                for (int nt = 0; nt < 4; nt++) {
                    int n = n0 + wn + nt * 16 + l15;
                    int bb = n >> 11, t = n & 2047;
                    ((unsigned short*)C_)[((size_t)bb * 1024 + m) * 2048 + t] =
                        f2bf(acc[mt][nt][r] + bm);
                }
            }
    } else {
        #pragma unroll
        for (int nt = 0; nt < 4; nt++) {
            int n = n0 + wn + nt * 16 + l15;
            float bv = bias[n];
            #pragma unroll
            for (int mt = 0; mt < 4; mt++)
                #pragma unroll
                for (int r = 0; r < 4; r++) {
                    int m = m0 + wm + mt * 16 + quad * 4 + r;
                    float val = acc[mt][nt][r] + bv;
                    if (C_MODE == 1) ((float*)C_)[(size_t)m * N + n] = val;
                    else ((unsigned short*)C_)[(size_t)m * N + n] = f2bf(val);
                }
        }
    }
}

extern "C" void kernel_launch(void* const* d_in, const int* in_sizes, int n_in,
                              void* d_out, int out_size, void* d_ws, size_t ws_size,
                              hipStream_t stream)
{
    const float* q  = (const float*)d_in[0];
    const float* k  = (const float*)d_in[1];
    const float* v  = (const float*)d_in[2];
    const int*   mk = (const int*)d_in[3];
    const float* Wq = (const float*)d_in[4];
    const float* bq = (const float*)d_in[5];
    const float* Wk = (const float*)d_in[6];
    const float* bk = (const float*)d_in[7];
    const float* Wv = (const float*)d_in[8];
    const float* bv = (const float*)d_in[9];
    const float* Wo = (const float*)d_in[10];
    const float* bo = (const float*)d_in[11];
    float* out = (float*)d_out;

    unsigned short* wsb = (unsigned short*)d_ws;
    const dim3 gA(T_SEQ / QBLK, NHEAD, B_SZ);   // 16 x 16 x 2 = 512 blocks

    if (ws_size >= (size_t)64 * 1024 * 1024) {
        // Path A: pre-convert to bf16; m97-style global_load_lds GEMMs.
        unsigned short* Qb  = wsb;
        unsigned short* Kb  = wsb + INP_E;
        unsigned short* Vb  = wsb + 2 * INP_E;
        unsigned short* Wqb = wsb + 3 * INP_E;
        unsigned short* Wkb = wsb + 3 * INP_E + W_E;
        unsigned short* Wvb = wsb + 3 * INP_E + 2 * W_E;
        unsigned short* Wob = wsb + 3 * INP_E + 3 * W_E;
        unsigned short* Qp  = wsb + 4 * INP_E;
        unsigned short* Kp  = wsb + 5 * INP_E;
        unsigned short* Vt  = wsb + 6 * INP_E;
        unsigned short* AO  = wsb + 7 * INP_E;       // end = 64MB

        cvt_all<<<8192, 256, 0, stream>>>(q, k, v, Wq, Wk, Wv, Wo, wsb);
        gemm_qkv<<<dim3(256, 1, 3), 256, 0, stream>>>(
            Qb, Kb, Vb, Wqb, Wkb, Wvb, bq, bk, bv, Qp, Kp, Vt);
        attn_kernel<<<gA, 512, 0, stream>>>(Qp, Kp, Vt, mk, AO);
        gemm_o<<<dim3(512, 1, 1), 256, 0, stream>>>(AO, Wob, bo, out);
    } else {
        // Path C fallback: in-GEMM convert (32MB ws), legacy kernels.
        unsigned short* Qp = wsb;
        unsigned short* Kp = wsb + INP_E;
        unsigned short* Vt = wsb + 2 * INP_E;
        unsigned short* AO = wsb + 3 * INP_E;
        const dim3 gN(DMODEL / 128, M_ROWS / 128);
        const dim3 gV(M_ROWS / 128, DMODEL / 128);
        gemm_bt_cvt<0, 0, 0><<<gN, 256, 0, stream>>>(q, Wq, bq, Qp, M_ROWS, DMODEL, DMODEL);
        gemm_bt_cvt<0, 0, 0><<<gN, 256, 0, stream>>>(k, Wk, bk, Kp, M_ROWS, DMODEL, DMODEL);
        gemm_bt_cvt<0, 0, 2><<<gV, 256, 0, stream>>>(Wv, v, bv, Vt, DMODEL, M_ROWS, DMODEL);
        attn_kernel<<<gA, 512, 0, stream>>>(Qp, Kp, Vt, mk, AO);
        gemm_bt_cvt<1, 0, 1><<<gN, 256, 0, stream>>>(AO, Wo, bo, out, M_ROWS, DMODEL, DMODEL);
    }
}

// Round 7
// 224.944 us; speedup vs baseline: 1.1035x; 1.0308x over previous
//
#include <hip/hip_runtime.h>
#include <stdint.h>

// Problem constants (B,T,D,H fixed by the reference)
#define B_SZ 2
#define T_SEQ 2048
#define DMODEL 1024
#define NHEAD 16
#define DKH 64
#define M_ROWS (B_SZ * T_SEQ)   // 4096

#define LDT 72    // padded LDS row stride (bf16) for legacy-path sP

#define INP_E  4194304u   // 4M elems per input tensor
#define W_E    1048576u   // 1M elems per weight

typedef __bf16 bf16x8 __attribute__((ext_vector_type(8)));
typedef float  f32x4  __attribute__((ext_vector_type(4)));

__device__ __forceinline__ unsigned short f2bf(float f) {
    unsigned u = __builtin_bit_cast(unsigned, f);
    u += 0x7fffu + ((u >> 16) & 1u);   // RNE
    return (unsigned short)(u >> 16);
}
// 8 consecutive fp32 -> 8 bf16 packed in a uint4
__device__ __forceinline__ uint4 cvt8(const float* p) {
    float4 f0 = *(const float4*)p, f1 = *(const float4*)(p + 4);
    uint4 r;
    r.x = (unsigned)f2bf(f0.x) | ((unsigned)f2bf(f0.y) << 16);
    r.y = (unsigned)f2bf(f0.z) | ((unsigned)f2bf(f0.w) << 16);
    r.z = (unsigned)f2bf(f1.x) | ((unsigned)f2bf(f1.y) << 16);
    r.w = (unsigned)f2bf(f1.z) | ((unsigned)f2bf(f1.w) << 16);
    return r;
}

// Async global->LDS. LDS dest = wave-uniform base + lane*size (m104/m108).
__device__ __forceinline__ void async16(const unsigned short* g, unsigned short* l) {
    __builtin_amdgcn_global_load_lds(
        (const __attribute__((address_space(1))) void*)g,
        (__attribute__((address_space(3))) void*)l, 16, 0, 0);
}
__device__ __forceinline__ void async4(const unsigned short* g, unsigned short* l) {
    __builtin_amdgcn_global_load_lds(
        (const __attribute__((address_space(1))) void*)g,
        (__attribute__((address_space(3))) void*)l, 4, 0, 0);
}

// One-shot fp32 -> bf16 conversion of q,k,v + 4 weights into ws.
__global__ __launch_bounds__(256) void cvt_all(
    const float* __restrict__ q, const float* __restrict__ k, const float* __restrict__ v,
    const float* __restrict__ wq, const float* __restrict__ wk,
    const float* __restrict__ wv, const float* __restrict__ wo,
    unsigned short* __restrict__ wsb)
{
    int blk = blockIdx.x;
    const float* src; unsigned short* dst; int lb;
    if      (blk < 2048) { src = q;  dst = wsb;                       lb = blk; }
    else if (blk < 4096) { src = k;  dst = wsb + INP_E;               lb = blk - 2048; }
    else if (blk < 6144) { src = v;  dst = wsb + 2 * INP_E;           lb = blk - 4096; }
    else if (blk < 6656) { src = wq; dst = wsb + 3 * INP_E;           lb = blk - 6144; }
    else if (blk < 7168) { src = wk; dst = wsb + 3 * INP_E + W_E;     lb = blk - 6656; }
    else if (blk < 7680) { src = wv; dst = wsb + 3 * INP_E + 2 * W_E; lb = blk - 7168; }
    else                 { src = wo; dst = wsb + 3 * INP_E + 3 * W_E; lb = blk - 7680; }
    size_t i = ((size_t)lb * 256 + threadIdx.x) * 8;
    *(uint4*)&dst[i] = cvt8(src + i);
}

// ---------------- m97-style GEMM core ----------------
template<int C_MODE, int MT>
__device__ __forceinline__ void gemm_core(
    const unsigned short* __restrict__ A, const unsigned short* __restrict__ W,
    const float* __restrict__ bias, void* __restrict__ C,
    int N, int K, int bx, int by,
    unsigned short* sA, unsigned short* sB)
{
    const int tid  = threadIdx.x;
    const int wave = tid >> 6, lane = tid & 63;
    const int quad = lane >> 4, l15 = lane & 15;
    const int TM = MT * 32;
    const int m0 = by * TM, n0 = bx * 128;
    const int wm = (wave & 1) * (MT * 16), wn = (wave >> 1) * 64;

    f32x4 acc[MT][4] = {};

    for (int k0 = 0; k0 < K; k0 += 64) {
        __syncthreads();                      // prev iteration's LDS reads done
        #pragma unroll
        for (int i = 0; i < MT; i++) {        // A: TM rows x 8 chunks
            int c   = tid + 256 * i;
            int row = c >> 3;
            int gk  = ((c & 7) ^ (row & 7)) * 8;
            int sb  = (wave * 64 + 256 * i) * 8;
            async16(&A[(size_t)(m0 + row) * K + k0 + gk], sA + sb);
        }
        #pragma unroll
        for (int i = 0; i < 4; i++) {         // B: 128 rows x 8 chunks
            int c   = tid + 256 * i;
            int row = c >> 3;
            int gk  = ((c & 7) ^ (row & 7)) * 8;
            int sb  = (wave * 64 + 256 * i) * 8;
            async16(&W[(size_t)(n0 + row) * K + k0 + gk], sB + sb);
        }
        __syncthreads();                      // drains vmcnt(0): data landed
        const int sw = l15 & 7;
        #pragma unroll
        for (int ks = 0; ks < 2; ks++) {
            bf16x8 af[MT], bfv[4];
            #pragma unroll
            for (int mt = 0; mt < MT; mt++)
                af[mt] = *(const bf16x8*)&sA[(wm + mt * 16 + l15) * 64 +
                                             (((ks * 4 + quad) ^ sw) * 8)];
            #pragma unroll
            for (int nt = 0; nt < 4; nt++)
                bfv[nt] = *(const bf16x8*)&sB[(wn + nt * 16 + l15) * 64 +
                                              (((ks * 4 + quad) ^ sw) * 8)];
            #pragma unroll
            for (int mt = 0; mt < MT; mt++)
                #pragma unroll
                for (int nt = 0; nt < 4; nt++)
                    acc[mt][nt] = __builtin_amdgcn_mfma_f32_16x16x32_bf16(
                        af[mt], bfv[nt], acc[mt][nt], 0, 0, 0);
        }
    }

    if (C_MODE == 2) {
        #pragma unroll
        for (int mt = 0; mt < MT; mt++) {
            #pragma unroll
            for (int r = 0; r < 4; r++) {
                int m = m0 + wm + mt * 16 + quad * 4 + r;
                float bm = bias[m];
                #pragma unroll
                for (int nt = 0; nt < 4; nt++) {
                    int n = n0 + wn + nt * 16 + l15;
                    int bb = n >> 11, t = n & 2047;
                    ((unsigned short*)C)[((size_t)bb * 1024 + m) * 2048 + t] =
                        f2bf(acc[mt][nt][r] + bm);
                }
            }
        }
    } else {
        #pragma unroll
        for (int nt = 0; nt < 4; nt++) {
            int n = n0 + wn + nt * 16 + l15;
            float bv = bias[n];
            #pragma unroll
            for (int mt = 0; mt < MT; mt++) {
                #pragma unroll
                for (int r = 0; r < 4; r++) {
                    int m = m0 + wm + mt * 16 + quad * 4 + r;   // D row = quad*4+reg
                    float val = acc[mt][nt][r] + bv;
                    if (C_MODE == 1) ((float*)C)[(size_t)m * N + n] = val;
                    else ((unsigned short*)C)[(size_t)m * N + n] = f2bf(val);
                }
            }
        }
    }
}

// Q,K,V projections + V-transpose batched: grid (256,1,3) = 768 blocks (~3/CU).
__global__ __launch_bounds__(256) void gemm_qkv(
    const unsigned short* __restrict__ Qb, const unsigned short* __restrict__ Kb,
    const unsigned short* __restrict__ Vb,
    const unsigned short* __restrict__ Wqb, const unsigned short* __restrict__ Wkb,
    const unsigned short* __restrict__ Wvb,
    const float* __restrict__ bq, const float* __restrict__ bk, const float* __restrict__ bv,
    unsigned short* __restrict__ Qp, unsigned short* __restrict__ Kp,
    unsigned short* __restrict__ Vt)
{
    __shared__ __align__(16) unsigned short sA[128 * 64];
    __shared__ __align__(16) unsigned short sB[128 * 64];
    const int z = blockIdx.z, id = blockIdx.x;
    if (z < 2) {
        gemm_core<0, 4>(z ? Kb : Qb, z ? Wkb : Wqb, z ? bk : bq, z ? Kp : Qp,
                        DMODEL, DMODEL, id & 7, id >> 3, sA, sB);
    } else {
        gemm_core<2, 4>(Wvb, Vb, bv, Vt, M_ROWS, DMODEL, id & 31, id >> 5, sA, sB);
    }
}

// Output projection: 64x128 tiles -> 512 blocks.
__global__ __launch_bounds__(256) void gemm_o(
    const unsigned short* __restrict__ AO, const unsigned short* __restrict__ Wob,
    const float* __restrict__ bo, float* __restrict__ out)
{
    __shared__ __align__(16) unsigned short sA[64 * 64];
    __shared__ __align__(16) unsigned short sB[128 * 64];
    const int id = blockIdx.x;
    gemm_core<1, 2>(AO, Wob, bo, out, DMODEL, DMODEL, id & 7, id >> 3, sA, sB);
}

// ---------------- flash attention: in-register P^T, zero-shuffle, KV split ----------------
// Round-7: swapped QK^T (mfma(K,Q) -> S^T[key][q], lane-local softmax) + key-permuted
// V layout so PV's B-operand IS the lane's own P values (k-slot quad*8+j holds key
// (j>>2)*16+quad*4+(j&3); A-side V staged in the same permutation via width-4
// global_load_lds). Eliminates 32 ds_write + 4 ds_read of P per wave-tile AND the
// write->lgkmcnt->read serialization. sP freed: LDS 77KB -> 40KB. Output is O^T;
// group merge via padded f32[128][65] overlaid on dead K/V LDS.
#define QBLK 128
#define KVB 64

__global__ __launch_bounds__(512, 4) void attn_kernel(
    const unsigned short* __restrict__ Qp,
    const unsigned short* __restrict__ Kp,
    const unsigned short* __restrict__ Vt,
    const int* __restrict__ maskp,     // [B,T], nonzero = keep
    unsigned short* __restrict__ Op)
{
    __shared__ __align__(16) unsigned char sMEM[40960];
    unsigned short* sK  = (unsigned short*)sMEM;            // [2 tiles][64 key][64 d] chunk-swz, 16KB
    unsigned short* sV  = (unsigned short*)(sMEM + 16384);  // [2 tiles][64 d][64 permkey] chunk-swz, 16KB
    float*          smf = (float*)(sMEM + 32768);           // [2048] mask add table, 8KB

    const int tid  = threadIdx.x;
    const int wave = tid >> 6, lane = tid & 63;
    const int g    = wave >> 2, wl = wave & 3;
    const int quad = lane >> 4, l15 = lane & 15;
    const int qblk = blockIdx.x, h = blockIdx.y, b = blockIdx.z;

    const float SCL2 = 0.125f * 1.44269504089f;   // 1/sqrt(DK) * log2(e)
    const float MNEG = -30000.f;                  // exp2(-30000+x) == 0

    // Q fragments (B-operand: col=q=l15, k=d=quad*8+j), rows wl*32 + mt*16 + l15
    bf16x8 aq[2][2];
    #pragma unroll
    for (int mt = 0; mt < 2; mt++) {
        const int qrow = qblk * QBLK + wl * 32 + mt * 16 + l15;
        const unsigned short* qptr =
            Qp + (size_t)(b * T_SEQ + qrow) * DMODEL + h * DKH + quad * 8;
        aq[mt][0] = *(const bf16x8*)qptr;
        aq[mt][1] = *(const bf16x8*)(qptr + 32);
    }

    const unsigned short* Kb_ = Kp + (size_t)b * T_SEQ * DMODEL + h * DKH;
    const unsigned short* VtB = Vt + ((size_t)b * DMODEL + h * DKH) * T_SEQ;

    // ---- staging address precompute (loop-invariant) ----
    // K: 2 width-16 loads/thread/round (2 tiles x 8KB), same scheme as proven gemm staging.
    int kOff[2], kSb[2];
    #pragma unroll
    for (int i = 0; i < 2; i++) {
        int c = tid + 512 * i;
        int tile = c >> 9, cc = c & 511;
        int row = cc >> 3;
        int gk = ((cc & 7) ^ (row & 7)) * 8;
        kOff[i] = (tile * 64 + row) * DMODEL + gk;        // + rr*128*DMODEL at use
        kSb[i]  = (wave * 64 + 512 * i) * 8;              // element offset in sK
    }
    // V: 8 width-4 loads/thread/round into the PERMUTED layout.
    // LDS byte pos P -> (tile,row,stored chunk,slot) -> logical perm 4B index f ->
    // (g2,qq,r2) -> global key offset. 4B = 2 consecutive global keys.
    int vOff[8], vSb[8];
    #pragma unroll
    for (int i = 0; i < 8; i++) {
        int P    = wave * 2048 + i * 256 + lane * 4;      // byte pos in 16KB V region
        int tile = P >> 13;
        int rp   = P & 8191;
        int row  = rp >> 7;                               // d row
        int cb   = (rp >> 4) & 7;                         // stored chunk
        int slot = (rp >> 2) & 3;                         // 4B slot in chunk
        int c    = cb ^ (row & 7);                        // logical perm chunk
        int f    = c * 4 + slot;                          // perm 4B index 0..31
        int g2   = ((f >> 4) << 1) | ((f >> 1) & 1);
        int qq   = (f >> 2) & 3;
        int r2   = (f & 1) * 2;
        int keyoff = g2 * 16 + qq * 4 + r2;
        vOff[i] = row * T_SEQ + tile * 64 + keyoff;       // + rr*128 at use
        vSb[i]  = (wave * 2048 + i * 256) >> 1;           // wave-uniform dest (shorts)
    }

    f32x4 O[2][4] = {};
    float l_r[2] = {0.f, 0.f};

    // expand mask once (visible after round-0's post-stage barrier)
    #pragma unroll
    for (int j = 0; j < 4; j++) {
        int i = tid + 512 * j;
        smf[i] = maskp[b * T_SEQ + i] ? 0.f : MNEG;
    }

    const int sw = l15 & 7;
    for (int rr = 0; rr < T_SEQ / (2 * KVB); ++rr) {   // 16 rounds, 2 tiles each
        // ---- stage both tiles (group g will compute tile g this round) ----
        #pragma unroll
        for (int i = 0; i < 2; i++)
            async16(&Kb_[(size_t)rr * 128 * DMODEL + kOff[i]], sK + kSb[i]);
        #pragma unroll
        for (int i = 0; i < 8; i++)
            async4(&VtB[(size_t)rr * 128 + vOff[i]], sV + vSb[i]);
        __syncthreads();   // drains vmcnt: tiles landed (and smf on round 0)

        const unsigned short* sKp = sK + g * 4096;
        const unsigned short* sVp = sV + g * 4096;
        const int s0 = (2 * rr + g) * KVB;

        // ---- S^T = K Q^T : row = key = kt*16+quad*4+r, col = q = mt*16+l15 ----
        f32x4 ST[2][4];
        __builtin_amdgcn_s_setprio(1);
        #pragma unroll
        for (int kt = 0; kt < 4; kt++) {
            const unsigned short* kr = &sKp[(kt * 16 + l15) * 64];
            const bf16x8 kf0 = *(const bf16x8*)&kr[(quad ^ sw) * 8];
            const bf16x8 kf1 = *(const bf16x8*)&kr[((quad + 4) ^ sw) * 8];
            #pragma unroll
            for (int mt = 0; mt < 2; mt++) {
                f32x4 z = {};
                z = __builtin_amdgcn_mfma_f32_16x16x32_bf16(kf0, aq[mt][0], z, 0, 0, 0);
                z = __builtin_amdgcn_mfma_f32_16x16x32_bf16(kf1, aq[mt][1], z, 0, 0, 0);
                ST[mt][kt] = z;
            }
        }
        __builtin_amdgcn_s_setprio(0);

        // ---- softmax fully in-register; pack P^T into B-fragments ----
        bf16x8 pb[2][2];
        #pragma unroll
        for (int kt = 0; kt < 4; kt++) {
            float4 m4 = *(const float4*)&smf[s0 + kt * 16 + quad * 4];  // broadcast b128
            float ma[4] = {m4.x, m4.y, m4.z, m4.w};
            #pragma unroll
            for (int mt = 0; mt < 2; mt++) {
                #pragma unroll
                for (int r = 0; r < 4; r++) {
                    float p = __builtin_amdgcn_exp2f(fmaf(ST[mt][kt][r], SCL2, ma[r]));
                    l_r[mt] += p;
                    pb[mt][kt >> 1][(kt & 1) * 4 + r] = (__bf16)p;   // key (kt)*16+quad*4+r
                }
            }
        }

        // ---- O^T += V^T P^T (A = permuted V^T rows d, B = in-register P^T) ----
        __builtin_amdgcn_s_setprio(1);
        #pragma unroll
        for (int nt = 0; nt < 4; nt++) {
            const unsigned short* vr = &sVp[(nt * 16 + l15) * 64];
            const bf16x8 vf0 = *(const bf16x8*)&vr[(quad ^ sw) * 8];
            const bf16x8 vf1 = *(const bf16x8*)&vr[((quad + 4) ^ sw) * 8];
            #pragma unroll
            for (int mt = 0; mt < 2; mt++) {
                O[mt][nt] = __builtin_amdgcn_mfma_f32_16x16x32_bf16(
                    vf0, pb[mt][0], O[mt][nt], 0, 0, 0);
                O[mt][nt] = __builtin_amdgcn_mfma_f32_16x16x32_bf16(
                    vf1, pb[mt][1], O[mt][nt], 0, 0, 0);
            }
        }
        __builtin_amdgcn_s_setprio(0);

        __syncthreads();   // all reads of this round's tiles done before next stage
    }

    // ---- l: sum across quads (q = mt*16 + l15 lives in 4 quad-copies) ----
    #pragma unroll
    for (int mt = 0; mt < 2; mt++) {
        float l = l_r[mt];
        l += __shfl_xor(l, 16);
        l += __shfl_xor(l, 32);
        l_r[mt] = l;
    }

    // ---- group merge via dead LDS: OM f32[128][65] (padded), LM[128] ----
    float* OM = (float*)sMEM;             // 33280 B
    float* LM = (float*)(sMEM + 33280);   // 512 B
    if (g == 1) {
        #pragma unroll
        for (int mt = 0; mt < 2; mt++) {
            int row = wl * 32 + mt * 16 + l15;
            if (quad == 0) LM[row] = l_r[mt];
            #pragma unroll
            for (int nt = 0; nt < 4; nt++)
                #pragma unroll
                for (int r = 0; r < 4; r++)
                    OM[row * 65 + nt * 16 + quad * 4 + r] = O[mt][nt][r];
        }
    }
    __syncthreads();
    if (g == 0) {
        #pragma unroll
        for (int mt = 0; mt < 2; mt++) {
            int row = wl * 32 + mt * 16 + l15;
            float inv = 1.0f / fmaxf(l_r[mt] + LM[row], 1e-30f);
            int qg = qblk * QBLK + row;
            unsigned short* op = Op + (size_t)(b * T_SEQ + qg) * DMODEL + h * DKH;
            #pragma unroll
            for (int nt = 0; nt < 4; nt++) {
                ushort4 w;
                w.x = f2bf((O[mt][nt][0] + OM[row * 65 + nt * 16 + quad * 4 + 0]) * inv);
                w.y = f2bf((O[mt][nt][1] + OM[row * 65 + nt * 16 + quad * 4 + 1]) * inv);
                w.z = f2bf((O[mt][nt][2] + OM[row * 65 + nt * 16 + quad * 4 + 2]) * inv);
                w.w = f2bf((O[mt][nt][3] + OM[row * 65 + nt * 16 + quad * 4 + 3]) * inv);
                *(ushort4*)&op[nt * 16 + quad * 4] = w;
            }
        }
    }
}

// ---------------- legacy fp32-staging GEMM (fallback path only) ----------------
template<int A_BF16, int W_BF16, int C_MODE>
__global__ __launch_bounds__(256) void gemm_bt_cvt(
    const void* __restrict__ A_, const void* __restrict__ W_,
    const float* __restrict__ bias, void* __restrict__ C_,
    int M, int N, int K)
{
    __shared__ __align__(16) unsigned short sA[128 * LDT];
    __shared__ __align__(16) unsigned short sB[128 * LDT];
    const int tid  = threadIdx.x;
    const int wave = tid >> 6, lane = tid & 63;
    const int quad = lane >> 4, l15 = lane & 15;
    const int m0 = blockIdx.y * 128, n0 = blockIdx.x * 128;
    const int wm = (wave & 1) * 64, wn = (wave >> 1) * 64;
    f32x4 acc[4][4] = {};
    for (int k0 = 0; k0 < K; k0 += 64) {
        __syncthreads();
        #pragma unroll
        for (int i = 0; i < 4; i++) {
            int c = tid + 256 * i;
            int row = c >> 3, koff = (c & 7) * 8;
            if (A_BF16)
                *(uint4*)&sA[row * LDT + koff] =
                    *(const uint4*)&((const unsigned short*)A_)[(size_t)(m0 + row) * K + k0 + koff];
            else
                *(uint4*)&sA[row * LDT + koff] =
                    cvt8((const float*)A_ + (size_t)(m0 + row) * K + k0 + koff);
            if (W_BF16)
                *(uint4*)&sB[row * LDT + koff] =
                    *(const uint4*)&((const unsigned short*)W_)[(size_t)(n0 + row) * K + k0 + koff];
            else
                *(uint4*)&sB[row * LDT + koff] =
                    cvt8((const float*)W_ + (size_t)(n0 + row) * K + k0 + koff);
        }
        __syncthreads();
        #pragma unroll
        for (int ks = 0; ks < 2; ks++) {
            bf16x8 af[4], bfr[4];
            #pragma unroll
            for (int mt = 0; mt < 4; mt++)
                af[mt] = *(const bf16x8*)&sA[(wm + mt * 16 + l15) * LDT + ks * 32 + quad * 8];
            #pragma unroll
            for (int nt = 0; nt < 4; nt++)
                bfr[nt] = *(const bf16x8*)&sB[(wn + nt * 16 + l15) * LDT + ks * 32 + quad * 8];
            #pragma unroll
            for (int mt = 0; mt < 4; mt++)
                #pragma unroll
                for (int nt = 0; nt < 4; nt++)
                    acc[mt][nt] = __builtin_amdgcn_mfma_f32_16x16x32_bf16(
                        af[mt], bfr[nt], acc[mt][nt], 0, 0, 0);
        }
    }
    if (C_MODE == 2) {
        #pragma unroll
        for (int mt = 0; mt < 4; mt++)
            #pragma unroll
            for (int r = 0; r < 4; r++) {
                int m = m0 + wm + mt * 16 + quad * 4 + r;
                float bm = bias[m];
                #pragma unroll
                for (int nt = 0; nt < 4; nt++) {
                    int n = n0 + wn + nt * 16 + l15;
                    int bb = n >> 11, t = n & 2047;
                    ((unsigned short*)C_)[((size_t)bb * 1024 + m) * 2048 + t] =
                        f2bf(acc[mt][nt][r] + bm);
                }
            }
    } else {
        #pragma unroll
        for (int nt = 0; nt < 4; nt++) {
            int n = n0 + wn + nt * 16 + l15;
            float bv = bias[n];
            #pragma unroll
            for (int mt = 0; mt < 4; mt++)
                #pragma unroll
                for (int r = 0; r < 4; r++) {
                    int m = m0 + wm + mt * 16 + quad * 4 + r;
                    float val = acc[mt][nt][r] + bv;
                    if (C_MODE == 1) ((float*)C_)[(size_t)m * N + n] = val;
                    else ((unsigned short*)C_)[(size_t)m * N + n] = f2bf(val);
                }
        }
    }
}

extern "C" void kernel_launch(void* const* d_in, const int* in_sizes, int n_in,
                              void* d_out, int out_size, void* d_ws, size_t ws_size,
                              hipStream_t stream)
{
    const float* q  = (const float*)d_in[0];
    const float* k  = (const float*)d_in[1];
    const float* v  = (const float*)d_in[2];
    const int*   mk = (const int*)d_in[3];
    const float* Wq = (const float*)d_in[4];
    const float* bq = (const float*)d_in[5];
    const float* Wk = (const float*)d_in[6];
    const float* bk = (const float*)d_in[7];
    const float* Wv = (const float*)d_in[8];
    const float* bv = (const float*)d_in[9];
    const float* Wo = (const float*)d_in[10];
    const float* bo = (const float*)d_in[11];
    float* out = (float*)d_out;

    unsigned short* wsb = (unsigned short*)d_ws;
    const dim3 gA(T_SEQ / QBLK, NHEAD, B_SZ);   // 16 x 16 x 2 = 512 blocks

    if (ws_size >= (size_t)64 * 1024 * 1024) {
        // Path A: pre-convert to bf16; m97-style global_load_lds GEMMs.
        unsigned short* Qb  = wsb;
        unsigned short* Kb  = wsb + INP_E;
        unsigned short* Vb  = wsb + 2 * INP_E;
        unsigned short* Wqb = wsb + 3 * INP_E;
        unsigned short* Wkb = wsb + 3 * INP_E + W_E;
        unsigned short* Wvb = wsb + 3 * INP_E + 2 * W_E;
        unsigned short* Wob = wsb + 3 * INP_E + 3 * W_E;
        unsigned short* Qp  = wsb + 4 * INP_E;
        unsigned short* Kp  = wsb + 5 * INP_E;
        unsigned short* Vt  = wsb + 6 * INP_E;
        unsigned short* AO  = wsb + 7 * INP_E;       // end = 64MB

        cvt_all<<<8192, 256, 0, stream>>>(q, k, v, Wq, Wk, Wv, Wo, wsb);
        gemm_qkv<<<dim3(256, 1, 3), 256, 0, stream>>>(
            Qb, Kb, Vb, Wqb, Wkb, Wvb, bq, bk, bv, Qp, Kp, Vt);
        attn_kernel<<<gA, 512, 0, stream>>>(Qp, Kp, Vt, mk, AO);
        gemm_o<<<dim3(512, 1, 1), 256, 0, stream>>>(AO, Wob, bo, out);
    } else {
        // Path C fallback: in-GEMM convert (32MB ws), legacy kernels.
        unsigned short* Qp = wsb;
        unsigned short* Kp = wsb + INP_E;
        unsigned short* Vt = wsb + 2 * INP_E;
        unsigned short* AO = wsb + 3 * INP_E;
        const dim3 gN(DMODEL / 128, M_ROWS / 128);
        const dim3 gV(M_ROWS / 128, DMODEL / 128);
        gemm_bt_cvt<0, 0, 0><<<gN, 256, 0, stream>>>(q, Wq, bq, Qp, M_ROWS, DMODEL, DMODEL);
        gemm_bt_cvt<0, 0, 0><<<gN, 256, 0, stream>>>(k, Wk, bk, Kp, M_ROWS, DMODEL, DMODEL);
        gemm_bt_cvt<0, 0, 2><<<gV, 256, 0, stream>>>(Wv, v, bv, Vt, DMODEL, M_ROWS, DMODEL);
        attn_kernel<<<gA, 512, 0, stream>>>(Qp, Kp, Vt, mk, AO);
        gemm_bt_cvt<1, 0, 1><<<gN, 256, 0, stream>>>(AO, Wo, bo, out, M_ROWS, DMODEL, DMODEL);
    }
}

// Round 9
// 223.583 us; speedup vs baseline: 1.1102x; 1.0061x over previous
//
#include <hip/hip_runtime.h>
#include <stdint.h>

// Problem constants (B,T,D,H fixed by the reference)
#define B_SZ 2
#define T_SEQ 2048
#define DMODEL 1024
#define NHEAD 16
#define DKH 64
#define M_ROWS (B_SZ * T_SEQ)   // 4096

#define LDT 72    // padded LDS row stride (bf16) for legacy-path sP

#define INP_E  4194304u   // 4M elems per input tensor
#define W_E    1048576u   // 1M elems per weight

typedef __bf16 bf16x8 __attribute__((ext_vector_type(8)));
typedef float  f32x4  __attribute__((ext_vector_type(4)));

__device__ __forceinline__ unsigned short f2bf(float f) {
    unsigned u = __builtin_bit_cast(unsigned, f);
    u += 0x7fffu + ((u >> 16) & 1u);   // RNE
    return (unsigned short)(u >> 16);
}
// 8 consecutive fp32 -> 8 bf16 packed in a uint4
__device__ __forceinline__ uint4 cvt8(const float* p) {
    float4 f0 = *(const float4*)p, f1 = *(const float4*)(p + 4);
    uint4 r;
    r.x = (unsigned)f2bf(f0.x) | ((unsigned)f2bf(f0.y) << 16);
    r.y = (unsigned)f2bf(f0.z) | ((unsigned)f2bf(f0.w) << 16);
    r.z = (unsigned)f2bf(f1.x) | ((unsigned)f2bf(f1.y) << 16);
    r.w = (unsigned)f2bf(f1.z) | ((unsigned)f2bf(f1.w) << 16);
    return r;
}

// Async global->LDS. LDS dest = wave-uniform base + lane*size (m104/m108).
__device__ __forceinline__ void async16(const unsigned short* g, unsigned short* l) {
    __builtin_amdgcn_global_load_lds(
        (const __attribute__((address_space(1))) void*)g,
        (__attribute__((address_space(3))) void*)l, 16, 0, 0);
}
__device__ __forceinline__ void async4(const unsigned short* g, unsigned short* l) {
    __builtin_amdgcn_global_load_lds(
        (const __attribute__((address_space(1))) void*)g,
        (__attribute__((address_space(3))) void*)l, 4, 0, 0);
}

// One-shot fp32 -> bf16 conversion of q,k,v + 4 weights into ws.
__global__ __launch_bounds__(256) void cvt_all(
    const float* __restrict__ q, const float* __restrict__ k, const float* __restrict__ v,
    const float* __restrict__ wq, const float* __restrict__ wk,
    const float* __restrict__ wv, const float* __restrict__ wo,
    unsigned short* __restrict__ wsb)
{
    int blk = blockIdx.x;
    const float* src; unsigned short* dst; int lb;
    if      (blk < 2048) { src = q;  dst = wsb;                       lb = blk; }
    else if (blk < 4096) { src = k;  dst = wsb + INP_E;               lb = blk - 2048; }
    else if (blk < 6144) { src = v;  dst = wsb + 2 * INP_E;           lb = blk - 4096; }
    else if (blk < 6656) { src = wq; dst = wsb + 3 * INP_E;           lb = blk - 6144; }
    else if (blk < 7168) { src = wk; dst = wsb + 3 * INP_E + W_E;     lb = blk - 6656; }
    else if (blk < 7680) { src = wv; dst = wsb + 3 * INP_E + 2 * W_E; lb = blk - 7168; }
    else                 { src = wo; dst = wsb + 3 * INP_E + 3 * W_E; lb = blk - 7680; }
    size_t i = ((size_t)lb * 256 + threadIdx.x) * 8;
    *(uint4*)&dst[i] = cvt8(src + i);
}

// ---------------- m97-style GEMM core ----------------
template<int C_MODE, int MT>
__device__ __forceinline__ void gemm_core(
    const unsigned short* __restrict__ A, const unsigned short* __restrict__ W,
    const float* __restrict__ bias, void* __restrict__ C,
    int N, int K, int bx, int by,
    unsigned short* sA, unsigned short* sB)
{
    const int tid  = threadIdx.x;
    const int wave = tid >> 6, lane = tid & 63;
    const int quad = lane >> 4, l15 = lane & 15;
    const int TM = MT * 32;
    const int m0 = by * TM, n0 = bx * 128;
    const int wm = (wave & 1) * (MT * 16), wn = (wave >> 1) * 64;

    f32x4 acc[MT][4] = {};

    for (int k0 = 0; k0 < K; k0 += 64) {
        __syncthreads();                      // prev iteration's LDS reads done
        #pragma unroll
        for (int i = 0; i < MT; i++) {        // A: TM rows x 8 chunks
            int c   = tid + 256 * i;
            int row = c >> 3;
            int gk  = ((c & 7) ^ (row & 7)) * 8;
            int sb  = (wave * 64 + 256 * i) * 8;
            async16(&A[(size_t)(m0 + row) * K + k0 + gk], sA + sb);
        }
        #pragma unroll
        for (int i = 0; i < 4; i++) {         // B: 128 rows x 8 chunks
            int c   = tid + 256 * i;
            int row = c >> 3;
            int gk  = ((c & 7) ^ (row & 7)) * 8;
            int sb  = (wave * 64 + 256 * i) * 8;
            async16(&W[(size_t)(n0 + row) * K + k0 + gk], sB + sb);
        }
        __syncthreads();                      // drains vmcnt(0): data landed
        const int sw = l15 & 7;
        #pragma unroll
        for (int ks = 0; ks < 2; ks++) {
            bf16x8 af[MT], bfv[4];
            #pragma unroll
            for (int mt = 0; mt < MT; mt++)
                af[mt] = *(const bf16x8*)&sA[(wm + mt * 16 + l15) * 64 +
                                             (((ks * 4 + quad) ^ sw) * 8)];
            #pragma unroll
            for (int nt = 0; nt < 4; nt++)
                bfv[nt] = *(const bf16x8*)&sB[(wn + nt * 16 + l15) * 64 +
                                              (((ks * 4 + quad) ^ sw) * 8)];
            #pragma unroll
            for (int mt = 0; mt < MT; mt++)
                #pragma unroll
                for (int nt = 0; nt < 4; nt++)
                    acc[mt][nt] = __builtin_amdgcn_mfma_f32_16x16x32_bf16(
                        af[mt], bfv[nt], acc[mt][nt], 0, 0, 0);
        }
    }

    if (C_MODE == 2) {
        #pragma unroll
        for (int mt = 0; mt < MT; mt++) {
            #pragma unroll
            for (int r = 0; r < 4; r++) {
                int m = m0 + wm + mt * 16 + quad * 4 + r;
                float bm = bias[m];
                #pragma unroll
                for (int nt = 0; nt < 4; nt++) {
                    int n = n0 + wn + nt * 16 + l15;
                    int bb = n >> 11, t = n & 2047;
                    ((unsigned short*)C)[((size_t)bb * 1024 + m) * 2048 + t] =
                        f2bf(acc[mt][nt][r] + bm);
                }
            }
        }
    } else {
        #pragma unroll
        for (int nt = 0; nt < 4; nt++) {
            int n = n0 + wn + nt * 16 + l15;
            float bv = bias[n];
            #pragma unroll
            for (int mt = 0; mt < MT; mt++) {
                #pragma unroll
                for (int r = 0; r < 4; r++) {
                    int m = m0 + wm + mt * 16 + quad * 4 + r;   // D row = quad*4+reg
                    float val = acc[mt][nt][r] + bv;
                    if (C_MODE == 1) ((float*)C)[(size_t)m * N + n] = val;
                    else ((unsigned short*)C)[(size_t)m * N + n] = f2bf(val);
                }
            }
        }
    }
}

// Q,K,V projections + V-transpose batched: grid (256,1,3) = 768 blocks (~3/CU).
__global__ __launch_bounds__(256) void gemm_qkv(
    const unsigned short* __restrict__ Qb, const unsigned short* __restrict__ Kb,
    const unsigned short* __restrict__ Vb,
    const unsigned short* __restrict__ Wqb, const unsigned short* __restrict__ Wkb,
    const unsigned short* __restrict__ Wvb,
    const float* __restrict__ bq, const float* __restrict__ bk, const float* __restrict__ bv,
    unsigned short* __restrict__ Qp, unsigned short* __restrict__ Kp,
    unsigned short* __restrict__ Vt)
{
    __shared__ __align__(16) unsigned short sA[128 * 64];
    __shared__ __align__(16) unsigned short sB[128 * 64];
    const int z = blockIdx.z, id = blockIdx.x;
    if (z < 2) {
        gemm_core<0, 4>(z ? Kb : Qb, z ? Wkb : Wqb, z ? bk : bq, z ? Kp : Qp,
                        DMODEL, DMODEL, id & 7, id >> 3, sA, sB);
    } else {
        gemm_core<2, 4>(Wvb, Vb, bv, Vt, M_ROWS, DMODEL, id & 31, id >> 5, sA, sB);
    }
}

// Output projection: 64x128 tiles -> 512 blocks.
__global__ __launch_bounds__(256) void gemm_o(
    const unsigned short* __restrict__ AO, const unsigned short* __restrict__ Wob,
    const float* __restrict__ bo, float* __restrict__ out)
{
    __shared__ __align__(16) unsigned short sA[64 * 64];
    __shared__ __align__(16) unsigned short sB[128 * 64];
    const int id = blockIdx.x;
    gemm_core<1, 2>(AO, Wob, bo, out, DMODEL, DMODEL, id & 7, id >> 3, sA, sB);
}

// ---------------- flash attention: in-register P^T + DOUBLE-BUFFERED rounds ----------------
// Round-8 (resubmitted after broker timeout): R7 showed all pipes <50% busy (Mfma 24,
// VALU 39, LDS ~35%, HBM 19%) — latency-bound. The single-buffered round structure
// exposed the full staging latency at the post-stage vmcnt(0) drain every round.
// Fix: double-buffer the K/V ROUNDS (2 tiles each): prologue stages round 0; each
// iteration issues round rr+1's stage into buf^1 BEFORE computing round rr; the
// single end-of-round __syncthreads drains vmcnt only after ~2500cy of compute
// covered the latency. LDS 72KB -> still 2 blocks/CU, 16 waves/CU.
// Everything else identical to R7 (in-register P^T, permuted V, zero-shuffle).
#define QBLK 128
#define KVB 64

__global__ __launch_bounds__(512, 4) void attn_kernel(
    const unsigned short* __restrict__ Qp,
    const unsigned short* __restrict__ Kp,
    const unsigned short* __restrict__ Vt,
    const int* __restrict__ maskp,     // [B,T], nonzero = keep
    unsigned short* __restrict__ Op)
{
    __shared__ __align__(16) unsigned char sMEM[73728];
    unsigned short* sK  = (unsigned short*)sMEM;            // [2 buf][2 tiles][64 key][64 d], 32KB
    unsigned short* sV  = (unsigned short*)(sMEM + 32768);  // [2 buf][2 tiles][64 d][64 permkey], 32KB
    float*          smf = (float*)(sMEM + 65536);           // [2048] mask add table, 8KB

    const int tid  = threadIdx.x;
    const int wave = tid >> 6, lane = tid & 63;
    const int g    = wave >> 2, wl = wave & 3;
    const int quad = lane >> 4, l15 = lane & 15;
    const int qblk = blockIdx.x, h = blockIdx.y, b = blockIdx.z;

    const float SCL2 = 0.125f * 1.44269504089f;   // 1/sqrt(DK) * log2(e)
    const float MNEG = -30000.f;                  // exp2(-30000+x) == 0

    // Q fragments (B-operand: col=q=l15, k=d=quad*8+j), rows wl*32 + mt*16 + l15
    bf16x8 aq[2][2];
    #pragma unroll
    for (int mt = 0; mt < 2; mt++) {
        const int qrow = qblk * QBLK + wl * 32 + mt * 16 + l15;
        const unsigned short* qptr =
            Qp + (size_t)(b * T_SEQ + qrow) * DMODEL + h * DKH + quad * 8;
        aq[mt][0] = *(const bf16x8*)qptr;
        aq[mt][1] = *(const bf16x8*)(qptr + 32);
    }

    const unsigned short* Kb_ = Kp + (size_t)b * T_SEQ * DMODEL + h * DKH;
    const unsigned short* VtB = Vt + ((size_t)b * DMODEL + h * DKH) * T_SEQ;

    // ---- staging address precompute (loop-invariant) ----
    // K: 2 width-16 loads/thread/round (2 tiles x 8KB).
    int kOff[2], kSb[2];
    #pragma unroll
    for (int i = 0; i < 2; i++) {
        int c = tid + 512 * i;
        int tile = c >> 9, cc = c & 511;
        int row = cc >> 3;
        int gk = ((cc & 7) ^ (row & 7)) * 8;
        kOff[i] = (tile * 64 + row) * DMODEL + gk;        // + rr*128*DMODEL at use
        kSb[i]  = (wave * 64 + 512 * i) * 8;              // element offset within one buf
    }
    // V: 8 width-4 loads/thread/round into the PERMUTED layout.
    int vOff[8], vSb[8];
    #pragma unroll
    for (int i = 0; i < 8; i++) {
        int P    = wave * 2048 + i * 256 + lane * 4;      // byte pos in one 16KB V buf
        int tile = P >> 13;
        int rp   = P & 8191;
        int row  = rp >> 7;                               // d row
        int cb   = (rp >> 4) & 7;                         // stored chunk
        int slot = (rp >> 2) & 3;                         // 4B slot in chunk
        int c    = cb ^ (row & 7);                        // logical perm chunk
        int f    = c * 4 + slot;                          // perm 4B index 0..31
        int g2   = ((f >> 4) << 1) | ((f >> 1) & 1);
        int qq   = (f >> 2) & 3;
        int r2   = (f & 1) * 2;
        int keyoff = g2 * 16 + qq * 4 + r2;
        vOff[i] = row * T_SEQ + tile * 64 + keyoff;       // + rr*128 at use
        vSb[i]  = (wave * 2048 + i * 256) >> 1;           // wave-uniform dest (shorts)
    }

    f32x4 O[2][4] = {};
    float l_r[2] = {0.f, 0.f};

    // ---- prologue: stage round 0 into buf 0; expand mask ----
    #pragma unroll
    for (int i = 0; i < 2; i++)
        async16(&Kb_[kOff[i]], sK + kSb[i]);
    #pragma unroll
    for (int i = 0; i < 8; i++)
        async4(&VtB[vOff[i]], sV + vSb[i]);
    #pragma unroll
    for (int j = 0; j < 4; j++) {
        int i = tid + 512 * j;
        smf[i] = maskp[b * T_SEQ + i] ? 0.f : MNEG;
    }
    __syncthreads();   // drains round-0 stage; smf visible

    const int sw = l15 & 7;
    for (int rr = 0; rr < T_SEQ / (2 * KVB); ++rr) {   // 16 rounds, 2 tiles each
        const int cur = rr & 1;
        // ---- issue round rr+1's stage into the other buffer (overlaps compute) ----
        if (rr + 1 < T_SEQ / (2 * KVB)) {
            const int nb = cur ^ 1;
            #pragma unroll
            for (int i = 0; i < 2; i++)
                async16(&Kb_[(size_t)(rr + 1) * 128 * DMODEL + kOff[i]],
                        sK + nb * 8192 + kSb[i]);
            #pragma unroll
            for (int i = 0; i < 8; i++)
                async4(&VtB[(size_t)(rr + 1) * 128 + vOff[i]],
                       sV + nb * 8192 + vSb[i]);
        }

        const unsigned short* sKp = sK + cur * 8192 + g * 4096;
        const unsigned short* sVp = sV + cur * 8192 + g * 4096;
        const int s0 = (2 * rr + g) * KVB;

        // ---- S^T = K Q^T : row = key = kt*16+quad*4+r, col = q = mt*16+l15 ----
        f32x4 ST[2][4];
        __builtin_amdgcn_s_setprio(1);
        #pragma unroll
        for (int kt = 0; kt < 4; kt++) {
            const unsigned short* kr = &sKp[(kt * 16 + l15) * 64];
            const bf16x8 kf0 = *(const bf16x8*)&kr[(quad ^ sw) * 8];
            const bf16x8 kf1 = *(const bf16x8*)&kr[((quad + 4) ^ sw) * 8];
            #pragma unroll
            for (int mt = 0; mt < 2; mt++) {
                f32x4 z = {};
                z = __builtin_amdgcn_mfma_f32_16x16x32_bf16(kf0, aq[mt][0], z, 0, 0, 0);
                z = __builtin_amdgcn_mfma_f32_16x16x32_bf16(kf1, aq[mt][1], z, 0, 0, 0);
                ST[mt][kt] = z;
            }
        }
        __builtin_amdgcn_s_setprio(0);

        // ---- softmax fully in-register; pack P^T into B-fragments ----
        bf16x8 pb[2][2];
        #pragma unroll
        for (int kt = 0; kt < 4; kt++) {
            float4 m4 = *(const float4*)&smf[s0 + kt * 16 + quad * 4];  // broadcast b128
            float ma[4] = {m4.x, m4.y, m4.z, m4.w};
            #pragma unroll
            for (int mt = 0; mt < 2; mt++) {
                #pragma unroll
                for (int r = 0; r < 4; r++) {
                    float p = __builtin_amdgcn_exp2f(fmaf(ST[mt][kt][r], SCL2, ma[r]));
                    l_r[mt] += p;
                    pb[mt][kt >> 1][(kt & 1) * 4 + r] = (__bf16)p;   // key (kt)*16+quad*4+r
                }
            }
        }

        // ---- O^T += V^T P^T (A = permuted V^T rows d, B = in-register P^T) ----
        __builtin_amdgcn_s_setprio(1);
        #pragma unroll
        for (int nt = 0; nt < 4; nt++) {
            const unsigned short* vr = &sVp[(nt * 16 + l15) * 64];
            const bf16x8 vf0 = *(const bf16x8*)&vr[(quad ^ sw) * 8];
            const bf16x8 vf1 = *(const bf16x8*)&vr[((quad + 4) ^ sw) * 8];
            #pragma unroll
            for (int mt = 0; mt < 2; mt++) {
                O[mt][nt] = __builtin_amdgcn_mfma_f32_16x16x32_bf16(
                    vf0, pb[mt][0], O[mt][nt], 0, 0, 0);
                O[mt][nt] = __builtin_amdgcn_mfma_f32_16x16x32_bf16(
                    vf1, pb[mt][1], O[mt][nt], 0, 0, 0);
            }
        }
        __builtin_amdgcn_s_setprio(0);

        // single barrier: all reads of buf[cur] done before round rr+2 overwrites it;
        // also drains the rr+1 stage AFTER a full compute phase hid its latency.
        __syncthreads();
    }

    // ---- l: sum across quads (q = mt*16 + l15 lives in 4 quad-copies) ----
    #pragma unroll
    for (int mt = 0; mt < 2; mt++) {
        float l = l_r[mt];
        l += __shfl_xor(l, 16);
        l += __shfl_xor(l, 32);
        l_r[mt] = l;
    }

    // ---- group merge via dead LDS: OM f32[128][65] (padded), LM[128] ----
    float* OM = (float*)sMEM;             // 33280 B
    float* LM = (float*)(sMEM + 33280);   // 512 B
    if (g == 1) {
        #pragma unroll
        for (int mt = 0; mt < 2; mt++) {
            int row = wl * 32 + mt * 16 + l15;
            if (quad == 0) LM[row] = l_r[mt];
            #pragma unroll
            for (int nt = 0; nt < 4; nt++)
                #pragma unroll
                for (int r = 0; r < 4; r++)
                    OM[row * 65 + nt * 16 + quad * 4 + r] = O[mt][nt][r];
        }
    }
    __syncthreads();
    if (g == 0) {
        #pragma unroll
        for (int mt = 0; mt < 2; mt++) {
            int row = wl * 32 + mt * 16 + l15;
            float inv = 1.0f / fmaxf(l_r[mt] + LM[row], 1e-30f);
            int qg = qblk * QBLK + row;
            unsigned short* op = Op + (size_t)(b * T_SEQ + qg) * DMODEL + h * DKH;
            #pragma unroll
            for (int nt = 0; nt < 4; nt++) {
                ushort4 w;
                w.x = f2bf((O[mt][nt][0] + OM[row * 65 + nt * 16 + quad * 4 + 0]) * inv);
                w.y = f2bf((O[mt][nt][1] + OM[row * 65 + nt * 16 + quad * 4 + 1]) * inv);
                w.z = f2bf((O[mt][nt][2] + OM[row * 65 + nt * 16 + quad * 4 + 2]) * inv);
                w.w = f2bf((O[mt][nt][3] + OM[row * 65 + nt * 16 + quad * 4 + 3]) * inv);
                *(ushort4*)&op[nt * 16 + quad * 4] = w;
            }
        }
    }
}

// ---------------- legacy fp32-staging GEMM (fallback path only) ----------------
template<int A_BF16, int W_BF16, int C_MODE>
__global__ __launch_bounds__(256) void gemm_bt_cvt(
    const void* __restrict__ A_, const void* __restrict__ W_,
    const float* __restrict__ bias, void* __restrict__ C_,
    int M, int N, int K)
{
    __shared__ __align__(16) unsigned short sA[128 * LDT];
    __shared__ __align__(16) unsigned short sB[128 * LDT];
    const int tid  = threadIdx.x;
    const int wave = tid >> 6, lane = tid & 63;
    const int quad = lane >> 4, l15 = lane & 15;
    const int m0 = blockIdx.y * 128, n0 = blockIdx.x * 128;
    const int wm = (wave & 1) * 64, wn = (wave >> 1) * 64;
    f32x4 acc[4][4] = {};
    for (int k0 = 0; k0 < K; k0 += 64) {
        __syncthreads();
        #pragma unroll
        for (int i = 0; i < 4; i++) {
            int c = tid + 256 * i;
            int row = c >> 3, koff = (c & 7) * 8;
            if (A_BF16)
                *(uint4*)&sA[row * LDT + koff] =
                    *(const uint4*)&((const unsigned short*)A_)[(size_t)(m0 + row) * K + k0 + koff];
            else
                *(uint4*)&sA[row * LDT + koff] =
                    cvt8((const float*)A_ + (size_t)(m0 + row) * K + k0 + koff);
            if (W_BF16)
                *(uint4*)&sB[row * LDT + koff] =
                    *(const uint4*)&((const unsigned short*)W_)[(size_t)(n0 + row) * K + k0 + koff];
            else
                *(uint4*)&sB[row * LDT + koff] =
                    cvt8((const float*)W_ + (size_t)(n0 + row) * K + k0 + koff);
        }
        __syncthreads();
        #pragma unroll
        for (int ks = 0; ks < 2; ks++) {
            bf16x8 af[4], bfr[4];
            #pragma unroll
            for (int mt = 0; mt < 4; mt++)
                af[mt] = *(const bf16x8*)&sA[(wm + mt * 16 + l15) * LDT + ks * 32 + quad * 8];
            #pragma unroll
            for (int nt = 0; nt < 4; nt++)
                bfr[nt] = *(const bf16x8*)&sB[(wn + nt * 16 + l15) * LDT + ks * 32 + quad * 8];
            #pragma unroll
            for (int mt = 0; mt < 4; mt++)
                #pragma unroll
                for (int nt = 0; nt < 4; nt++)
                    acc[mt][nt] = __builtin_amdgcn_mfma_f32_16x16x32_bf16(
                        af[mt], bfr[nt], acc[mt][nt], 0, 0, 0);
        }
    }
    if (C_MODE == 2) {
        #pragma unroll
        for (int mt = 0; mt < 4; mt++)
            #pragma unroll
            for (int r = 0; r < 4; r++) {
                int m = m0 + wm + mt * 16 + quad * 4 + r;
                float bm = bias[m];
                #pragma unroll
                for (int nt = 0; nt < 4; nt++) {
                    int n = n0 + wn + nt * 16 + l15;
                    int bb = n >> 11, t = n & 2047;
                    ((unsigned short*)C_)[((size_t)bb * 1024 + m) * 2048 + t] =
                        f2bf(acc[mt][nt][r] + bm);
                }
            }
    } else {
        #pragma unroll
        for (int nt = 0; nt < 4; nt++) {
            int n = n0 + wn + nt * 16 + l15;
            float bv = bias[n];
            #pragma unroll
            for (int mt = 0; mt < 4; mt++)
                #pragma unroll
                for (int r = 0; r < 4; r++) {
                    int m = m0 + wm + mt * 16 + quad * 4 + r;
                    float val = acc[mt][nt][r] + bv;
                    if (C_MODE == 1) ((float*)C_)[(size_t)m * N + n] = val;
                    else ((unsigned short*)C_)[(size_t)m * N + n] = f2bf(val);
                }
        }
    }
}

extern "C" void kernel_launch(void* const* d_in, const int* in_sizes, int n_in,
                              void* d_out, int out_size, void* d_ws, size_t ws_size,
                              hipStream_t stream)
{
    const float* q  = (const float*)d_in[0];
    const float* k  = (const float*)d_in[1];
    const float* v  = (const float*)d_in[2];
    const int*   mk = (const int*)d_in[3];
    const float* Wq = (const float*)d_in[4];
    const float* bq = (const float*)d_in[5];
    const float* Wk = (const float*)d_in[6];
    const float* bk = (const float*)d_in[7];
    const float* Wv = (const float*)d_in[8];
    const float* bv = (const float*)d_in[9];
    const float* Wo = (const float*)d_in[10];
    const float* bo = (const float*)d_in[11];
    float* out = (float*)d_out;

    unsigned short* wsb = (unsigned short*)d_ws;
    const dim3 gA(T_SEQ / QBLK, NHEAD, B_SZ);   // 16 x 16 x 2 = 512 blocks

    if (ws_size >= (size_t)64 * 1024 * 1024) {
        // Path A: pre-convert to bf16; m97-style global_load_lds GEMMs.
        unsigned short* Qb  = wsb;
        unsigned short* Kb  = wsb + INP_E;
        unsigned short* Vb  = wsb + 2 * INP_E;
        unsigned short* Wqb = wsb + 3 * INP_E;
        unsigned short* Wkb = wsb + 3 * INP_E + W_E;
        unsigned short* Wvb = wsb + 3 * INP_E + 2 * W_E;
        unsigned short* Wob = wsb + 3 * INP_E + 3 * W_E;
        unsigned short* Qp  = wsb + 4 * INP_E;
        unsigned short* Kp  = wsb + 5 * INP_E;
        unsigned short* Vt  = wsb + 6 * INP_E;
        unsigned short* AO  = wsb + 7 * INP_E;       // end = 64MB

        cvt_all<<<8192, 256, 0, stream>>>(q, k, v, Wq, Wk, Wv, Wo, wsb);
        gemm_qkv<<<dim3(256, 1, 3), 256, 0, stream>>>(
            Qb, Kb, Vb, Wqb, Wkb, Wvb, bq, bk, bv, Qp, Kp, Vt);
        attn_kernel<<<gA, 512, 0, stream>>>(Qp, Kp, Vt, mk, AO);
        gemm_o<<<dim3(512, 1, 1), 256, 0, stream>>>(AO, Wob, bo, out);
    } else {
        // Path C fallback: in-GEMM convert (32MB ws), legacy kernels.
        unsigned short* Qp = wsb;
        unsigned short* Kp = wsb + INP_E;
        unsigned short* Vt = wsb + 2 * INP_E;
        unsigned short* AO = wsb + 3 * INP_E;
        const dim3 gN(DMODEL / 128, M_ROWS / 128);
        const dim3 gV(M_ROWS / 128, DMODEL / 128);
        gemm_bt_cvt<0, 0, 0><<<gN, 256, 0, stream>>>(q, Wq, bq, Qp, M_ROWS, DMODEL, DMODEL);
        gemm_bt_cvt<0, 0, 0><<<gN, 256, 0, stream>>>(k, Wk, bk, Kp, M_ROWS, DMODEL, DMODEL);
        gemm_bt_cvt<0, 0, 2><<<gV, 256, 0, stream>>>(Wv, v, bv, Vt, DMODEL, M_ROWS, DMODEL);
        attn_kernel<<<gA, 512, 0, stream>>>(Qp, Kp, Vt, mk, AO);
        gemm_bt_cvt<1, 0, 1><<<gN, 256, 0, stream>>>(AO, Wo, bo, out, M_ROWS, DMODEL, DMODEL);
    }
}